// Round 1
// baseline (4364.784 us; speedup 1.0000x reference)
//
#include <hip/hip_runtime.h>
#include <hip/hip_fp16.h>
#include <stdint.h>

// MDRNN: 2-level bidirectional LSTM, S=2048 steps, B=64, H=128, I=256, O=88.
// Scan v6: TWO same-direction chains time-multiplexed per WG (64 WGs x 512 thr,
// shared Whh registers) so each chain's latency tail / LDS-read stall is filled
// by the partner chain's independent fdot2 stream; 1 barrier per 2 chain-steps.
// h exchange via 16-slot LDS ring (80B-strided chunks, conflict-free b128 reads)
// which doubles as tout history -> block flush every 8 steps by all 512 threads
// (removes wave-0's divergent per-step tout drain). Quad reduce-scatter (12 ops
// vs 16 all-reduce) with post-reduce x-preact inject.

typedef _Float16 f16;
typedef _Float16 f16x2 __attribute__((ext_vector_type(2)));
typedef _Float16 f16x4 __attribute__((ext_vector_type(4)));
typedef _Float16 f16x8 __attribute__((ext_vector_type(8)));
typedef float f32x4 __attribute__((ext_vector_type(4)));

#if defined(__has_builtin)
#if __has_builtin(__builtin_amdgcn_fdot2)
#define HAVE_FDOT2 1
#endif
#if __has_builtin(__builtin_amdgcn_rcpf)
#define FRCP(x) __builtin_amdgcn_rcpf(x)
#else
#define FRCP(x) (1.f / (x))
#endif
#if __has_builtin(__builtin_amdgcn_exp2f)
#define FEXP2(x) __builtin_amdgcn_exp2f(x)
#else
#define FEXP2(x) __exp2f(x)
#endif
#endif

static __device__ __forceinline__ float fdot2a(uint32_t a, uint32_t b, float c) {
#ifdef HAVE_FDOT2
    return __builtin_amdgcn_fdot2(__builtin_bit_cast(f16x2, a),
                                  __builtin_bit_cast(f16x2, b), c, false);
#else
    f16x2 av = __builtin_bit_cast(f16x2, a), bv = __builtin_bit_cast(f16x2, b);
    return c + (float)av.x * (float)bv.x + (float)av.y * (float)bv.y;
#endif
}

template <int CTRL>
static __device__ __forceinline__ float qperm(float v) {
    int r = __builtin_amdgcn_update_dpp(0, __builtin_bit_cast(int, v), CTRL, 0xf, 0xf, true);
    return __builtin_bit_cast(float, r);
}

// ---------------- conversions ----------------

__global__ __launch_bounds__(256) void k_convert_x(const float* __restrict__ x,
                                                   f16* __restrict__ xh) {
    size_t id = (size_t)blockIdx.x * 256 + threadIdx.x;  // 4,194,304 threads x 8 elems
    const float4* src = (const float4*)(x + id * 8);
    float4 v0 = src[0], v1 = src[1];
    f16x8 o = {(f16)v0.x, (f16)v0.y, (f16)v0.z, (f16)v0.w,
               (f16)v1.x, (f16)v1.y, (f16)v1.z, (f16)v1.w};
    *(f16x8*)(xh + id * 8) = o;
}

__global__ __launch_bounds__(256) void k_convert_w(const float* __restrict__ src,
                                                   f16* __restrict__ dst, int n8) {
    int id = blockIdx.x * 256 + threadIdx.x;
    if (id >= n8) return;
    const float4* sp = (const float4*)(src + (size_t)id * 8);
    float4 v0 = sp[0], v1 = sp[1];
    f16x8 o = {(f16)v0.x, (f16)v0.y, (f16)v0.z, (f16)v0.w,
               (f16)v1.x, (f16)v1.y, (f16)v1.z, (f16)v1.w};
    *(f16x8*)(dst + (size_t)id * 8) = o;
}

// ---------------- MFMA GEMM into block-transposed G, bias fused ----------------
// C layout: [s/8][b][n][s%8]  (M = b*2048+s, n = 0..1023); C[n] += bias0[n]+bias1[n]

#define BM 128
#define BN 128
#define BKK 32
#define LDT 40   // padded LDS row stride (fp16 elems)

__global__ __launch_bounds__(256) void k_gemm(const f16* __restrict__ A,
                                              const f16* __restrict__ B,
                                              f16* __restrict__ C,
                                              const float* __restrict__ bias0,
                                              const float* __restrict__ bias1,
                                              int M, int N, int K) {
    __shared__ __align__(16) f16 As[BM * LDT];
    __shared__ __align__(16) f16 Bs[BN * LDT];
    const int tid  = threadIdx.x;
    const int m0   = blockIdx.x * BM;
    const int n0   = blockIdx.y * BN;
    const int lane = tid & 63;
    const int wave = tid >> 6;
    const int wm   = (wave & 1) * 64;
    const int wn   = (wave >> 1) * 64;
    const int r    = tid >> 1;
    const int koff = (tid & 1) * 16;
    const int mrow = lane & 15;
    const int kof  = (lane >> 4) * 8;

    // per-thread bias for the 4 output columns (off critical path)
    float bb[4];
#pragma unroll
    for (int j = 0; j < 4; ++j) {
        int cn = n0 + wn + j * 16 + (lane & 15);
        bb[j] = bias0[cn] + bias1[cn];
    }

    f32x4 acc[4][4];
#pragma unroll
    for (int i = 0; i < 4; ++i)
#pragma unroll
        for (int j = 0; j < 4; ++j) acc[i][j] = (f32x4){0.f, 0.f, 0.f, 0.f};

    for (int k0 = 0; k0 < K; k0 += BKK) {
        uint4 a0 = *(const uint4*)(A + (size_t)(m0 + r) * K + k0 + koff);
        uint4 a1 = *(const uint4*)(A + (size_t)(m0 + r) * K + k0 + koff + 8);
        uint4 b0 = *(const uint4*)(B + (size_t)(n0 + r) * K + k0 + koff);
        uint4 b1 = *(const uint4*)(B + (size_t)(n0 + r) * K + k0 + koff + 8);
        *(uint4*)(As + r * LDT + koff)     = a0;
        *(uint4*)(As + r * LDT + koff + 8) = a1;
        *(uint4*)(Bs + r * LDT + koff)     = b0;
        *(uint4*)(Bs + r * LDT + koff + 8) = b1;
        __syncthreads();
        f16x8 af[4], bfr[4];
#pragma unroll
        for (int i = 0; i < 4; ++i)
            af[i] = *(const f16x8*)(As + (wm + i * 16 + mrow) * LDT + kof);
#pragma unroll
        for (int j = 0; j < 4; ++j)
            bfr[j] = *(const f16x8*)(Bs + (wn + j * 16 + mrow) * LDT + kof);
#pragma unroll
        for (int i = 0; i < 4; ++i)
#pragma unroll
            for (int j = 0; j < 4; ++j)
                acc[i][j] = __builtin_amdgcn_mfma_f32_16x16x32_f16(af[i], bfr[j], acc[i][j], 0, 0, 0);
        __syncthreads();
    }
    const int crow = (lane >> 4) * 4;
#pragma unroll
    for (int i = 0; i < 4; ++i) {
#pragma unroll
        for (int j = 0; j < 4; ++j) {
            int cn = n0 + wn + j * 16 + (lane & 15);
            int m  = m0 + wm + i * 16 + crow;
            int bbk = m >> 11;         // batch
            int s   = m & 2047;        // step
            f16x4 v = {(f16)(acc[i][j][0] + bb[j]), (f16)(acc[i][j][1] + bb[j]),
                       (f16)(acc[i][j][2] + bb[j]), (f16)(acc[i][j][3] + bb[j])};
            size_t addr = ((((size_t)(s >> 3) * 64 + bbk) * 1024) + cn) * 8 + (s & 7);
            *(f16x4*)(C + addr) = v;
        }
    }
}

// ---------------- recurrent LSTM scan ----------------
// One WG per (dir, batch-pair), 512 threads: u = t>>2 (hidden unit), kc = t&3
// (K-split lane / gate lane). Per chain-step: 64 fdot2 into 8 accumulators ->
// combine -> quad reduce-scatter (lane kc ends with full gate-kc sum) ->
// +x-preact -> unified activation (1 exp + 1 rcp) -> 4 quad-broadcasts ->
// replicated cell update. Two chains per barrier period.

// h ring layout per chain: 16 slots x (4 chunks * 80 B). Chunk c holds
// h[32c..32c+32) (64 B) at byte c*80 -> the 4 kc-group b128 reads land on
// disjoint bank quads {0-3}/{20-23}/{8-11}/{28-31}: conflict-free.

static __device__ __forceinline__ float lstm_step(
    f16* __restrict__ rb, int slr, int slw,
    const uint32_t (&w)[4][16], float gxb, int kc, int u,
    float kact, float Bact, float& c) {
    const f16* hpv = rb + slr * 160 + kc * 40;
    float p0a = 0.f, p1a = 0.f, p2a = 0.f, p3a = 0.f;
    float p0b = 0.f, p1b = 0.f, p2b = 0.f, p3b = 0.f;
#pragma unroll
    for (int jj = 0; jj < 4; ++jj) {
        uint4 hq = *(const uint4*)(hpv + jj * 8);
        p0a = fdot2a(w[0][4 * jj + 0], hq.x, p0a);
        p1a = fdot2a(w[1][4 * jj + 0], hq.x, p1a);
        p2a = fdot2a(w[2][4 * jj + 0], hq.x, p2a);
        p3a = fdot2a(w[3][4 * jj + 0], hq.x, p3a);
        p0b = fdot2a(w[0][4 * jj + 1], hq.y, p0b);
        p1b = fdot2a(w[1][4 * jj + 1], hq.y, p1b);
        p2b = fdot2a(w[2][4 * jj + 1], hq.y, p2b);
        p3b = fdot2a(w[3][4 * jj + 1], hq.y, p3b);
        p0a = fdot2a(w[0][4 * jj + 2], hq.z, p0a);
        p1a = fdot2a(w[1][4 * jj + 2], hq.z, p1a);
        p2a = fdot2a(w[2][4 * jj + 2], hq.z, p2a);
        p3a = fdot2a(w[3][4 * jj + 2], hq.z, p3a);
        p0b = fdot2a(w[0][4 * jj + 3], hq.w, p0b);
        p1b = fdot2a(w[1][4 * jj + 3], hq.w, p1b);
        p2b = fdot2a(w[2][4 * jj + 3], hq.w, p2b);
        p3b = fdot2a(w[3][4 * jj + 3], hq.w, p3b);
    }
    float p0 = p0a + p0b, p1 = p1a + p1b, p2 = p2a + p2b, p3 = p3a + p3b;
    // quad reduce-scatter: after 2 DPP stages lane kc holds the FULL sum of
    // gate kc only (12 ops vs 16 for all-reduce), x-preact injected post-reduce.
    const bool k1 = (kc & 1) != 0;
    const bool k2 = (kc & 2) != 0;
    float s1 = k1 ? p0 : p1;          // what the xor-1 partner needs
    float s2 = k1 ? p2 : p3;
    float r1 = qperm<0xB1>(s1);
    float r2 = qperm<0xB1>(s2);
    float b1 = (k1 ? p1 : p0) + r1;   // gate (kc&1), reduced over lane pair
    float b2 = (k1 ? p3 : p2) + r2;   // gate 2+(kc&1)
    float s3 = k2 ? b1 : b2;          // what the xor-2 partner needs
    float r3 = qperm<0x4E>(s3);
    float v  = (k2 ? b2 : b1) + r3 + gxb;   // full gate-kc preactivation
    // unified activation: act = 1 - B * rcp(1 + exp2(k*v))
    float act = __builtin_fmaf(-Bact, FRCP(1.f + FEXP2(v * kact)), 1.f);
    // quad-broadcast the 4 activated gates
    float gi = qperm<0x00>(act);
    float gf = qperm<0x55>(act);
    float gg = qperm<0xAA>(act);
    float go = qperm<0xFF>(act);
    c = __builtin_fmaf(gf, c, gi * gg);
    float tc = __builtin_fmaf(-2.f, FRCP(1.f + FEXP2(c * 2.8853900818f)), 1.f);
    float h = go * tc;
    if (kc == 0) *(rb + slw * 160 + ((u >> 5) * 40 + (u & 31))) = (f16)h;
    return h;
}

__global__ void __attribute__((amdgpu_flat_work_group_size(512, 512),
                               amdgpu_waves_per_eu(2, 2))) k_lstm(
    const f16* __restrict__ G,              // [S/8][64][1024][8], bias pre-added
    const f16* __restrict__ Whh,            // [2][512][128] fp16
    f16* __restrict__ tout,                 // [131072][256] fp16 (flags&1)
    float* __restrict__ hfin,               // [64][256] fp32 (flags&2)
    const int S, const int flags) {
    const int wg  = blockIdx.x;             // 64 WGs
    const int dir = wg >> 5;
    const int b0  = (wg & 31) * 2;          // chains b0, b0+1 (same dir -> shared Whh regs)
    const int t   = threadIdx.x;
    const int u   = t >> 2;
    const int kc  = t & 3;

    __shared__ __align__(16) f16 ring[2][16][160];   // [chain][slot][4*40 padded f16]

    uint32_t w[4][16];
#pragma unroll
    for (int q = 0; q < 4; ++q) {
        const uint4* wp = (const uint4*)(Whh + ((size_t)(dir * 512 + q * 128 + u) * 128 + kc * 32));
#pragma unroll
        for (int jj = 0; jj < 4; ++jj) {
            uint4 qd = wp[jj];
            w[q][4 * jj + 0] = qd.x; w[q][4 * jj + 1] = qd.y;
            w[q][4 * jj + 2] = qd.z; w[q][4 * jj + 3] = qd.w;
        }
    }
#pragma unroll
    for (int q = 0; q < 4; ++q)
#pragma unroll
        for (int i = 0; i < 16; ++i) __asm__("" : "+v"(w[q][i]));

    const int rowg = dir * 512 + kc * 128 + u;    // this thread's G row
    const float kact = (kc == 2) ? 2.8853900818f : 1.4426950409f;
    const float Bact = (kc == 2) ? 2.0f : 1.0f;

    // zero slot 15 of both rings (h(-1) = 0)
    {
        uint32_t* rz = (uint32_t*)ring;
        if (t < 80) { rz[1200 + t] = 0u; rz[2480 + t] = 0u; }
    }
    float cA = 0.f, hA = 0.f, cB = 0.f, hB = 0.f;
    __syncthreads();

    const f16* gpA = G + ((size_t)b0 * 1024 + rowg) * 8;
    const f16* gpB = G + ((size_t)(b0 + 1) * 1024 + rowg) * 8;

    // tout flush mapping: thread -> (chain q, step-in-block jf, 8B chunk c8)
    const int fq  = t >> 8;
    const int frm = t & 255;
    const int fjf = frm >> 5;
    const int fc8 = frm & 31;

    uint4 gblkA = *(const uint4*)gpA;             // steps 0..7
    uint4 gblkB = *(const uint4*)gpB;
    for (int sb = 0; sb < S; sb += 8) {
        const size_t nblk = (size_t)((sb + 8 < S) ? (sb >> 3) + 1 : (sb >> 3));
        uint4 gnA = *(const uint4*)(gpA + nblk * 524288);  // prefetch next block
        uint4 gnB = *(const uint4*)(gpB + nblk * 524288);
        if ((flags & 1) && sb > 0) {
            // flush previous block's 8 h-rows (slots disjoint from this block's
            // writes; race-free for 8 more barriers). 8 B per thread.
            const int sl = ((sb - 8) & 15) + fjf;
            const f16* rp = &ring[fq][sl][(fc8 >> 3) * 40 + (fc8 & 7) * 4];
            uint2 hv = *(const uint2*)rp;
            f16* op = tout + ((size_t)(b0 + fq) * 2048 + (sb - 8 + fjf)) * 256 + dir * 128 + fc8 * 4;
            *(uint2*)op = hv;
        }
#pragma unroll
        for (int j = 0; j < 8; ++j) {
            const int slr = (sb + j + 15) & 15;   // (s-1) & 15
            const int slw = (sb + j) & 15;
            {
                uint32_t d = ((const uint32_t*)&gblkA)[j >> 1];
                uint16_t us = (uint16_t)((j & 1) ? (d >> 16) : (d & 0xffff));
                float gxb = (float)__builtin_bit_cast(f16, us);
                hA = lstm_step(&ring[0][0][0], slr, slw, w, gxb, kc, u, kact, Bact, cA);
            }
            {
                uint32_t d = ((const uint32_t*)&gblkB)[j >> 1];
                uint16_t us = (uint16_t)((j & 1) ? (d >> 16) : (d & 0xffff));
                float gxb = (float)__builtin_bit_cast(f16, us);
                hB = lstm_step(&ring[1][0][0], slr, slw, w, gxb, kc, u, kact, Bact, cB);
            }
            // LDS-only drain + barrier: G prefetch stays in flight across it
            __asm__ __volatile__("s_waitcnt lgkmcnt(0)\n\ts_barrier" ::: "memory");
        }
        gblkA = gnA;
        gblkB = gnB;
    }
    if (flags & 1) {                              // flush final block (steps S-8..S-1)
        const int sl = ((S - 8) & 15) + fjf;
        const f16* rp = &ring[fq][sl][(fc8 >> 3) * 40 + (fc8 & 7) * 4];
        uint2 hv = *(const uint2*)rp;
        f16* op = tout + ((size_t)(b0 + fq) * 2048 + (S - 8 + fjf)) * 256 + dir * 128 + fc8 * 4;
        *(uint2*)op = hv;
    }
    if ((flags & 2) && kc == 0) {
        hfin[(b0 + 0) * 256 + dir * 128 + u] = hA;
        hfin[(b0 + 1) * 256 + dir * 128 + u] = hB;
    }
}

// ---------------- output projection ----------------

__global__ __launch_bounds__(128) void k_out(const float* __restrict__ hp,  // [64][256]
                                             const float* __restrict__ Wo,  // [88][256]
                                             const float* __restrict__ bo,  // [88]
                                             float* __restrict__ out) {     // [64][88]
    const int b = blockIdx.x;
    const int t = threadIdx.x;
    __shared__ float hs[256];
    hs[t] = hp[b * 256 + t];
    hs[t + 128] = hp[b * 256 + 128 + t];
    __syncthreads();
    if (t < 88) {
        float acc = bo[t];
        const float* wr = Wo + t * 256;
#pragma unroll 4
        for (int k = 0; k < 256; ++k) acc += wr[k] * hs[k];
        out[b * 88 + t] = acc;
    }
}

// ---------------- launch ----------------

extern "C" void kernel_launch(void* const* d_in, const int* in_sizes, int n_in,
                              void* d_out, int out_size, void* d_ws, size_t ws_size,
                              hipStream_t stream) {
    const float* x    = (const float*)d_in[0];
    const float* Wtih = (const float*)d_in[1];
    const float* Wthh = (const float*)d_in[2];
    const float* btih = (const float*)d_in[3];
    const float* bthh = (const float*)d_in[4];
    const float* Wpih = (const float*)d_in[5];
    const float* Wphh = (const float*)d_in[6];
    const float* bpih = (const float*)d_in[7];
    const float* bphh = (const float*)d_in[8];
    const float* Wo   = (const float*)d_in[9];
    const float* bo   = (const float*)d_in[10];

    char* ws = (char*)d_ws;
    f16*   xh    = (f16*)(ws + 0);            //  67,108,864 B  [131072][256]
    f16*   G     = (f16*)(ws + 67108864);     // 268,435,456 B  [256][64][1024][8]
    f16*   tout  = (f16*)(ws + 335544320);    //  67,108,864 B  [131072][256]
    f16*   wtih  = (f16*)(ws + 402653184);    //     524,288 B
    f16*   wthh  = (f16*)(ws + 403177472);    //     262,144 B
    f16*   wpih  = (f16*)(ws + 403439616);    //     524,288 B
    f16*   wphh  = (f16*)(ws + 403963904);    //     262,144 B
    float* hp    = (float*)(ws + 404226048);  //      65,536 B  (~405 MB total)

    k_convert_x<<<16384, 256, 0, stream>>>(x, xh);
    k_convert_w<<<128, 256, 0, stream>>>(Wtih, wtih, 32768);
    k_convert_w<<<64,  256, 0, stream>>>(Wthh, wthh, 16384);
    k_convert_w<<<128, 256, 0, stream>>>(Wpih, wpih, 32768);
    k_convert_w<<<64,  256, 0, stream>>>(Wphh, wphh, 16384);

    // G = blocked (xh @ Wt_ih^T) + bt_ih + bt_hh
    k_gemm<<<dim3(1024, 8), 256, 0, stream>>>(xh, wtih, G, btih, bthh, 131072, 1024, 256);
    // time-level scan -> tout (2 chains per WG)
    k_lstm<<<64, 512, 0, stream>>>(G, wthh, tout, nullptr, 2048, 1);
    // G = blocked (tout @ Wp_ih^T) + bp_ih + bp_hh
    k_gemm<<<dim3(1024, 8), 256, 0, stream>>>(tout, wpih, G, bpih, bphh, 131072, 1024, 256);
    // pitch-level scan -> final h
    k_lstm<<<64, 512, 0, stream>>>(G, wphh, nullptr, hp, 2048, 2);
    // output projection
    k_out<<<64, 128, 0, stream>>>(hp, Wo, bo, (float*)d_out);
}

// Round 2
// 4057.436 us; speedup vs baseline: 1.0757x; 1.0757x over previous
//
#include <hip/hip_runtime.h>
#include <hip/hip_fp16.h>
#include <stdint.h>

// MDRNN: 2-level bidirectional LSTM, S=2048 steps, B=64, H=128, I=256, O=88.
// Scan v7: two same-direction chains per WG (64 WGs x 512 thr, shared Whh
// registers), FUSED pair-step: all 8 LDS h-reads issued before any compute or
// ds_write (kills the v6 false write->read dependency that serialized the two
// chains), fdot2 streams and DPP/exp tails of both chains interleaved for dual
// independent latency chains. One barrier per pair. 16-slot LDS h-ring doubles
// as tout history, flushed every 8 steps by all 512 threads.

typedef _Float16 f16;
typedef _Float16 f16x2 __attribute__((ext_vector_type(2)));
typedef _Float16 f16x4 __attribute__((ext_vector_type(4)));
typedef _Float16 f16x8 __attribute__((ext_vector_type(8)));
typedef float f32x4 __attribute__((ext_vector_type(4)));

#if defined(__has_builtin)
#if __has_builtin(__builtin_amdgcn_fdot2)
#define HAVE_FDOT2 1
#endif
#if __has_builtin(__builtin_amdgcn_rcpf)
#define FRCP(x) __builtin_amdgcn_rcpf(x)
#else
#define FRCP(x) (1.f / (x))
#endif
#if __has_builtin(__builtin_amdgcn_exp2f)
#define FEXP2(x) __builtin_amdgcn_exp2f(x)
#else
#define FEXP2(x) __exp2f(x)
#endif
#endif

static __device__ __forceinline__ float fdot2a(uint32_t a, uint32_t b, float c) {
#ifdef HAVE_FDOT2
    return __builtin_amdgcn_fdot2(__builtin_bit_cast(f16x2, a),
                                  __builtin_bit_cast(f16x2, b), c, false);
#else
    f16x2 av = __builtin_bit_cast(f16x2, a), bv = __builtin_bit_cast(f16x2, b);
    return c + (float)av.x * (float)bv.x + (float)av.y * (float)bv.y;
#endif
}

template <int CTRL>
static __device__ __forceinline__ float qperm(float v) {
    int r = __builtin_amdgcn_update_dpp(0, __builtin_bit_cast(int, v), CTRL, 0xf, 0xf, true);
    return __builtin_bit_cast(float, r);
}

// ---------------- conversions ----------------

__global__ __launch_bounds__(256) void k_convert_x(const float* __restrict__ x,
                                                   f16* __restrict__ xh) {
    size_t id = (size_t)blockIdx.x * 256 + threadIdx.x;  // 4,194,304 threads x 8 elems
    const float4* src = (const float4*)(x + id * 8);
    float4 v0 = src[0], v1 = src[1];
    f16x8 o = {(f16)v0.x, (f16)v0.y, (f16)v0.z, (f16)v0.w,
               (f16)v1.x, (f16)v1.y, (f16)v1.z, (f16)v1.w};
    *(f16x8*)(xh + id * 8) = o;
}

__global__ __launch_bounds__(256) void k_convert_w(const float* __restrict__ src,
                                                   f16* __restrict__ dst, int n8) {
    int id = blockIdx.x * 256 + threadIdx.x;
    if (id >= n8) return;
    const float4* sp = (const float4*)(src + (size_t)id * 8);
    float4 v0 = sp[0], v1 = sp[1];
    f16x8 o = {(f16)v0.x, (f16)v0.y, (f16)v0.z, (f16)v0.w,
               (f16)v1.x, (f16)v1.y, (f16)v1.z, (f16)v1.w};
    *(f16x8*)(dst + (size_t)id * 8) = o;
}

// ---------------- MFMA GEMM into block-transposed G, bias fused ----------------
// C layout: [s/8][b][n][s%8]  (M = b*2048+s, n = 0..1023); C[n] += bias0[n]+bias1[n]

#define BM 128
#define BN 128
#define BKK 32
#define LDT 40   // padded LDS row stride (fp16 elems)

__global__ __launch_bounds__(256) void k_gemm(const f16* __restrict__ A,
                                              const f16* __restrict__ B,
                                              f16* __restrict__ C,
                                              const float* __restrict__ bias0,
                                              const float* __restrict__ bias1,
                                              int M, int N, int K) {
    __shared__ __align__(16) f16 As[BM * LDT];
    __shared__ __align__(16) f16 Bs[BN * LDT];
    const int tid  = threadIdx.x;
    const int m0   = blockIdx.x * BM;
    const int n0   = blockIdx.y * BN;
    const int lane = tid & 63;
    const int wave = tid >> 6;
    const int wm   = (wave & 1) * 64;
    const int wn   = (wave >> 1) * 64;
    const int r    = tid >> 1;
    const int koff = (tid & 1) * 16;
    const int mrow = lane & 15;
    const int kof  = (lane >> 4) * 8;

    // per-thread bias for the 4 output columns (off critical path)
    float bb[4];
#pragma unroll
    for (int j = 0; j < 4; ++j) {
        int cn = n0 + wn + j * 16 + (lane & 15);
        bb[j] = bias0[cn] + bias1[cn];
    }

    f32x4 acc[4][4];
#pragma unroll
    for (int i = 0; i < 4; ++i)
#pragma unroll
        for (int j = 0; j < 4; ++j) acc[i][j] = (f32x4){0.f, 0.f, 0.f, 0.f};

    for (int k0 = 0; k0 < K; k0 += BKK) {
        uint4 a0 = *(const uint4*)(A + (size_t)(m0 + r) * K + k0 + koff);
        uint4 a1 = *(const uint4*)(A + (size_t)(m0 + r) * K + k0 + koff + 8);
        uint4 b0 = *(const uint4*)(B + (size_t)(n0 + r) * K + k0 + koff);
        uint4 b1 = *(const uint4*)(B + (size_t)(n0 + r) * K + k0 + koff + 8);
        *(uint4*)(As + r * LDT + koff)     = a0;
        *(uint4*)(As + r * LDT + koff + 8) = a1;
        *(uint4*)(Bs + r * LDT + koff)     = b0;
        *(uint4*)(Bs + r * LDT + koff + 8) = b1;
        __syncthreads();
        f16x8 af[4], bfr[4];
#pragma unroll
        for (int i = 0; i < 4; ++i)
            af[i] = *(const f16x8*)(As + (wm + i * 16 + mrow) * LDT + kof);
#pragma unroll
        for (int j = 0; j < 4; ++j)
            bfr[j] = *(const f16x8*)(Bs + (wn + j * 16 + mrow) * LDT + kof);
#pragma unroll
        for (int i = 0; i < 4; ++i)
#pragma unroll
            for (int j = 0; j < 4; ++j)
                acc[i][j] = __builtin_amdgcn_mfma_f32_16x16x32_f16(af[i], bfr[j], acc[i][j], 0, 0, 0);
        __syncthreads();
    }
    const int crow = (lane >> 4) * 4;
#pragma unroll
    for (int i = 0; i < 4; ++i) {
#pragma unroll
        for (int j = 0; j < 4; ++j) {
            int cn = n0 + wn + j * 16 + (lane & 15);
            int m  = m0 + wm + i * 16 + crow;
            int bbk = m >> 11;         // batch
            int s   = m & 2047;        // step
            f16x4 v = {(f16)(acc[i][j][0] + bb[j]), (f16)(acc[i][j][1] + bb[j]),
                       (f16)(acc[i][j][2] + bb[j]), (f16)(acc[i][j][3] + bb[j])};
            size_t addr = ((((size_t)(s >> 3) * 64 + bbk) * 1024) + cn) * 8 + (s & 7);
            *(f16x4*)(C + addr) = v;
        }
    }
}

// ---------------- recurrent LSTM scan ----------------
// One WG per (dir, batch-pair), 512 threads: u = t>>2 (hidden unit), kc = t&3
// (K-split / gate lane). Fused pair-step: 8x ds_read_b128 (both chains) up
// front -> 128 interleaved fdot2 into 16 accumulators -> dual quad
// reduce-scatter -> dual unified activation -> dual cell update -> 2 ds_write.
// One barrier per pair.

// h ring layout per chain: 16 slots x (4 chunks * 80 B). Chunk c holds
// h[32c..32c+32) (64 B) at byte c*80 -> the 4 kc-group b128 reads land on
// disjoint bank quads {0-3}/{20-23}/{8-11}/{28-31}: conflict-free.

static __device__ __forceinline__ void lstm_step2(
    f16* __restrict__ rbA, f16* __restrict__ rbB, int slr, int slw,
    const uint32_t (&w)[4][16], float gxbA, float gxbB, int kc, int u,
    float kact, float Bact, float& cA, float& hA, float& cB, float& hB) {
    const f16* hpA = rbA + slr * 160 + kc * 40;
    const f16* hpB = rbB + slr * 160 + kc * 40;
    // ALL reads first (program-order before any ds_write of this step):
    uint4 hqA0 = *(const uint4*)(hpA + 0);
    uint4 hqA1 = *(const uint4*)(hpA + 8);
    uint4 hqA2 = *(const uint4*)(hpA + 16);
    uint4 hqA3 = *(const uint4*)(hpA + 24);
    uint4 hqB0 = *(const uint4*)(hpB + 0);
    uint4 hqB1 = *(const uint4*)(hpB + 8);
    uint4 hqB2 = *(const uint4*)(hpB + 16);
    uint4 hqB3 = *(const uint4*)(hpB + 24);

    float a0a = 0.f, a1a = 0.f, a2a = 0.f, a3a = 0.f;
    float a0b = 0.f, a1b = 0.f, a2b = 0.f, a3b = 0.f;
    float b0a = 0.f, b1a = 0.f, b2a = 0.f, b3a = 0.f;
    float b0b = 0.f, b1b = 0.f, b2b = 0.f, b3b = 0.f;
    const uint4 hqa[4] = {hqA0, hqA1, hqA2, hqA3};
    const uint4 hqb[4] = {hqB0, hqB1, hqB2, hqB3};
#pragma unroll
    for (int jj = 0; jj < 4; ++jj) {
        uint4 ha = hqa[jj], hb = hqb[jj];
        a0a = fdot2a(w[0][4 * jj + 0], ha.x, a0a);
        b0a = fdot2a(w[0][4 * jj + 0], hb.x, b0a);
        a1a = fdot2a(w[1][4 * jj + 0], ha.x, a1a);
        b1a = fdot2a(w[1][4 * jj + 0], hb.x, b1a);
        a2a = fdot2a(w[2][4 * jj + 0], ha.x, a2a);
        b2a = fdot2a(w[2][4 * jj + 0], hb.x, b2a);
        a3a = fdot2a(w[3][4 * jj + 0], ha.x, a3a);
        b3a = fdot2a(w[3][4 * jj + 0], hb.x, b3a);
        a0b = fdot2a(w[0][4 * jj + 1], ha.y, a0b);
        b0b = fdot2a(w[0][4 * jj + 1], hb.y, b0b);
        a1b = fdot2a(w[1][4 * jj + 1], ha.y, a1b);
        b1b = fdot2a(w[1][4 * jj + 1], hb.y, b1b);
        a2b = fdot2a(w[2][4 * jj + 1], ha.y, a2b);
        b2b = fdot2a(w[2][4 * jj + 1], hb.y, b2b);
        a3b = fdot2a(w[3][4 * jj + 1], ha.y, a3b);
        b3b = fdot2a(w[3][4 * jj + 1], hb.y, b3b);
        a0a = fdot2a(w[0][4 * jj + 2], ha.z, a0a);
        b0a = fdot2a(w[0][4 * jj + 2], hb.z, b0a);
        a1a = fdot2a(w[1][4 * jj + 2], ha.z, a1a);
        b1a = fdot2a(w[1][4 * jj + 2], hb.z, b1a);
        a2a = fdot2a(w[2][4 * jj + 2], ha.z, a2a);
        b2a = fdot2a(w[2][4 * jj + 2], hb.z, b2a);
        a3a = fdot2a(w[3][4 * jj + 2], ha.z, a3a);
        b3a = fdot2a(w[3][4 * jj + 2], hb.z, b3a);
        a0b = fdot2a(w[0][4 * jj + 3], ha.w, a0b);
        b0b = fdot2a(w[0][4 * jj + 3], hb.w, b0b);
        a1b = fdot2a(w[1][4 * jj + 3], ha.w, a1b);
        b1b = fdot2a(w[1][4 * jj + 3], hb.w, b1b);
        a2b = fdot2a(w[2][4 * jj + 3], ha.w, a2b);
        b2b = fdot2a(w[2][4 * jj + 3], hb.w, b2b);
        a3b = fdot2a(w[3][4 * jj + 3], ha.w, a3b);
        b3b = fdot2a(w[3][4 * jj + 3], hb.w, b3b);
    }
    float pA0 = a0a + a0b, pA1 = a1a + a1b, pA2 = a2a + a2b, pA3 = a3a + a3b;
    float pB0 = b0a + b0b, pB1 = b1a + b1b, pB2 = b2a + b2b, pB3 = b3a + b3b;

    // dual quad reduce-scatter: lane kc ends with the full gate-kc sum.
    const bool k1 = (kc & 1) != 0;
    const bool k2 = (kc & 2) != 0;
    float s1A = k1 ? pA0 : pA1, s1B = k1 ? pB0 : pB1;
    float s2A = k1 ? pA2 : pA3, s2B = k1 ? pB2 : pB3;
    float r1A = qperm<0xB1>(s1A), r1B = qperm<0xB1>(s1B);
    float r2A = qperm<0xB1>(s2A), r2B = qperm<0xB1>(s2B);
    float c1A = (k1 ? pA1 : pA0) + r1A, c1B = (k1 ? pB1 : pB0) + r1B;
    float c2A = (k1 ? pA3 : pA2) + r2A, c2B = (k1 ? pB3 : pB2) + r2B;
    float s3A = k2 ? c1A : c2A, s3B = k2 ? c1B : c2B;
    float r3A = qperm<0x4E>(s3A), r3B = qperm<0x4E>(s3B);
    float vA = (k2 ? c2A : c1A) + r3A + gxbA;
    float vB = (k2 ? c2B : c1B) + r3B + gxbB;
    // unified activation: act = 1 - B * rcp(1 + exp2(k*v))
    float eA = FEXP2(vA * kact), eB = FEXP2(vB * kact);
    float actA = __builtin_fmaf(-Bact, FRCP(1.f + eA), 1.f);
    float actB = __builtin_fmaf(-Bact, FRCP(1.f + eB), 1.f);
    // quad-broadcast the 4 activated gates (both chains)
    float giA = qperm<0x00>(actA), giB = qperm<0x00>(actB);
    float gfA = qperm<0x55>(actA), gfB = qperm<0x55>(actB);
    float ggA = qperm<0xAA>(actA), ggB = qperm<0xAA>(actB);
    float goA = qperm<0xFF>(actA), goB = qperm<0xFF>(actB);
    cA = __builtin_fmaf(gfA, cA, giA * ggA);
    cB = __builtin_fmaf(gfB, cB, giB * ggB);
    float tA = FEXP2(cA * 2.8853900818f), tB = FEXP2(cB * 2.8853900818f);
    float tcA = __builtin_fmaf(-2.f, FRCP(1.f + tA), 1.f);
    float tcB = __builtin_fmaf(-2.f, FRCP(1.f + tB), 1.f);
    hA = goA * tcA;
    hB = goB * tcB;
    if (kc == 0) {
        *(rbA + slw * 160 + ((u >> 5) * 40 + (u & 31))) = (f16)hA;
        *(rbB + slw * 160 + ((u >> 5) * 40 + (u & 31))) = (f16)hB;
    }
}

__global__ void __attribute__((amdgpu_flat_work_group_size(512, 512),
                               amdgpu_waves_per_eu(2, 2))) k_lstm(
    const f16* __restrict__ G,              // [S/8][64][1024][8], bias pre-added
    const f16* __restrict__ Whh,            // [2][512][128] fp16
    f16* __restrict__ tout,                 // [131072][256] fp16 (flags&1)
    float* __restrict__ hfin,               // [64][256] fp32 (flags&2)
    const int S, const int flags) {
    const int wg  = blockIdx.x;             // 64 WGs
    const int dir = wg >> 5;
    const int b0  = (wg & 31) * 2;          // chains b0, b0+1 (same dir -> shared Whh regs)
    const int t   = threadIdx.x;
    const int u   = t >> 2;
    const int kc  = t & 3;

    __shared__ __align__(16) f16 ring[2][16][160];   // [chain][slot][4*40 padded f16]

    uint32_t w[4][16];
#pragma unroll
    for (int q = 0; q < 4; ++q) {
        const uint4* wp = (const uint4*)(Whh + ((size_t)(dir * 512 + q * 128 + u) * 128 + kc * 32));
#pragma unroll
        for (int jj = 0; jj < 4; ++jj) {
            uint4 qd = wp[jj];
            w[q][4 * jj + 0] = qd.x; w[q][4 * jj + 1] = qd.y;
            w[q][4 * jj + 2] = qd.z; w[q][4 * jj + 3] = qd.w;
        }
    }
#pragma unroll
    for (int q = 0; q < 4; ++q)
#pragma unroll
        for (int i = 0; i < 16; ++i) __asm__("" : "+v"(w[q][i]));

    const int rowg = dir * 512 + kc * 128 + u;    // this thread's G row
    const float kact = (kc == 2) ? 2.8853900818f : 1.4426950409f;
    const float Bact = (kc == 2) ? 2.0f : 1.0f;

    // zero slot 15 of both rings (h(-1) = 0)
    {
        uint32_t* rz = (uint32_t*)ring;
        if (t < 80) { rz[1200 + t] = 0u; rz[2480 + t] = 0u; }
    }
    float cA = 0.f, hA = 0.f, cB = 0.f, hB = 0.f;
    __syncthreads();

    const f16* gpA = G + ((size_t)b0 * 1024 + rowg) * 8;
    const f16* gpB = G + ((size_t)(b0 + 1) * 1024 + rowg) * 8;

    // tout flush mapping: thread -> (chain q, step-in-block jf, 8B chunk c8)
    const int fq  = t >> 8;
    const int frm = t & 255;
    const int fjf = frm >> 5;
    const int fc8 = frm & 31;

    uint4 gblkA = *(const uint4*)gpA;             // steps 0..7
    uint4 gblkB = *(const uint4*)gpB;
    for (int sb = 0; sb < S; sb += 8) {
        const size_t nblk = (size_t)((sb + 8 < S) ? (sb >> 3) + 1 : (sb >> 3));
        uint4 gnA = *(const uint4*)(gpA + nblk * 524288);  // prefetch next block
        uint4 gnB = *(const uint4*)(gpB + nblk * 524288);
        if ((flags & 1) && sb > 0) {
            // flush previous block's 8 h-rows (slots disjoint from this block's
            // writes; race-free for 8 more barriers). 8 B per thread.
            const int sl = ((sb - 8) & 15) + fjf;
            const f16* rp = &ring[fq][sl][(fc8 >> 3) * 40 + (fc8 & 7) * 4];
            uint2 hv = *(const uint2*)rp;
            f16* op = tout + ((size_t)(b0 + fq) * 2048 + (sb - 8 + fjf)) * 256 + dir * 128 + fc8 * 4;
            *(uint2*)op = hv;
        }
#pragma unroll
        for (int j = 0; j < 8; ++j) {
            const int slr = (sb + j + 15) & 15;   // (s-1) & 15
            const int slw = (sb + j) & 15;
            uint32_t dA = ((const uint32_t*)&gblkA)[j >> 1];
            uint32_t dB = ((const uint32_t*)&gblkB)[j >> 1];
            uint16_t usA = (uint16_t)((j & 1) ? (dA >> 16) : (dA & 0xffff));
            uint16_t usB = (uint16_t)((j & 1) ? (dB >> 16) : (dB & 0xffff));
            float gxbA = (float)__builtin_bit_cast(f16, usA);
            float gxbB = (float)__builtin_bit_cast(f16, usB);
            lstm_step2(&ring[0][0][0], &ring[1][0][0], slr, slw, w,
                       gxbA, gxbB, kc, u, kact, Bact, cA, hA, cB, hB);
            // LDS-only drain + barrier: G prefetch stays in flight across it
            __asm__ __volatile__("s_waitcnt lgkmcnt(0)\n\ts_barrier" ::: "memory");
        }
        gblkA = gnA;
        gblkB = gnB;
    }
    if (flags & 1) {                              // flush final block (steps S-8..S-1)
        const int sl = ((S - 8) & 15) + fjf;
        const f16* rp = &ring[fq][sl][(fc8 >> 3) * 40 + (fc8 & 7) * 4];
        uint2 hv = *(const uint2*)rp;
        f16* op = tout + ((size_t)(b0 + fq) * 2048 + (S - 8 + fjf)) * 256 + dir * 128 + fc8 * 4;
        *(uint2*)op = hv;
    }
    if ((flags & 2) && kc == 0) {
        hfin[(b0 + 0) * 256 + dir * 128 + u] = hA;
        hfin[(b0 + 1) * 256 + dir * 128 + u] = hB;
    }
}

// ---------------- output projection ----------------

__global__ __launch_bounds__(128) void k_out(const float* __restrict__ hp,  // [64][256]
                                             const float* __restrict__ Wo,  // [88][256]
                                             const float* __restrict__ bo,  // [88]
                                             float* __restrict__ out) {     // [64][88]
    const int b = blockIdx.x;
    const int t = threadIdx.x;
    __shared__ float hs[256];
    hs[t] = hp[b * 256 + t];
    hs[t + 128] = hp[b * 256 + 128 + t];
    __syncthreads();
    if (t < 88) {
        float acc = bo[t];
        const float* wr = Wo + t * 256;
#pragma unroll 4
        for (int k = 0; k < 256; ++k) acc += wr[k] * hs[k];
        out[b * 88 + t] = acc;
    }
}

// ---------------- launch ----------------

extern "C" void kernel_launch(void* const* d_in, const int* in_sizes, int n_in,
                              void* d_out, int out_size, void* d_ws, size_t ws_size,
                              hipStream_t stream) {
    const float* x    = (const float*)d_in[0];
    const float* Wtih = (const float*)d_in[1];
    const float* Wthh = (const float*)d_in[2];
    const float* btih = (const float*)d_in[3];
    const float* bthh = (const float*)d_in[4];
    const float* Wpih = (const float*)d_in[5];
    const float* Wphh = (const float*)d_in[6];
    const float* bpih = (const float*)d_in[7];
    const float* bphh = (const float*)d_in[8];
    const float* Wo   = (const float*)d_in[9];
    const float* bo   = (const float*)d_in[10];

    char* ws = (char*)d_ws;
    f16*   xh    = (f16*)(ws + 0);            //  67,108,864 B  [131072][256]
    f16*   G     = (f16*)(ws + 67108864);     // 268,435,456 B  [256][64][1024][8]
    f16*   tout  = (f16*)(ws + 335544320);    //  67,108,864 B  [131072][256]
    f16*   wtih  = (f16*)(ws + 402653184);    //     524,288 B
    f16*   wthh  = (f16*)(ws + 403177472);    //     262,144 B
    f16*   wpih  = (f16*)(ws + 403439616);    //     524,288 B
    f16*   wphh  = (f16*)(ws + 403963904);    //     262,144 B
    float* hp    = (float*)(ws + 404226048);  //      65,536 B  (~405 MB total)

    k_convert_x<<<16384, 256, 0, stream>>>(x, xh);
    k_convert_w<<<128, 256, 0, stream>>>(Wtih, wtih, 32768);
    k_convert_w<<<64,  256, 0, stream>>>(Wthh, wthh, 16384);
    k_convert_w<<<128, 256, 0, stream>>>(Wpih, wpih, 32768);
    k_convert_w<<<64,  256, 0, stream>>>(Wphh, wphh, 16384);

    // G = blocked (xh @ Wt_ih^T) + bt_ih + bt_hh
    k_gemm<<<dim3(1024, 8), 256, 0, stream>>>(xh, wtih, G, btih, bthh, 131072, 1024, 256);
    // time-level scan -> tout (2 chains per WG, fused pair-step)
    k_lstm<<<64, 512, 0, stream>>>(G, wthh, tout, nullptr, 2048, 1);
    // G = blocked (tout @ Wp_ih^T) + bp_ih + bp_hh
    k_gemm<<<dim3(1024, 8), 256, 0, stream>>>(tout, wpih, G, bpih, bphh, 131072, 1024, 256);
    // pitch-level scan -> final h
    k_lstm<<<64, 512, 0, stream>>>(G, wphh, nullptr, hp, 2048, 2);
    // output projection
    k_out<<<64, 128, 0, stream>>>(hp, Wo, bo, (float*)d_out);
}

// Round 3
// 4029.826 us; speedup vs baseline: 1.0831x; 1.0069x over previous
//
#include <hip/hip_runtime.h>
#include <hip/hip_fp16.h>
#include <stdint.h>

// MDRNN: 2-level bidirectional LSTM, S=2048 steps, B=64, H=128, I=256, O=88.
// Scan v8: MFMA recurrence. 8 WGs x 512 thr, 16 chains/WG (chain = batch%16,
// dir/batch-block = WG). Whh & Wih rows PERMUTED to unit-major-gate-minor
// (row' = u*4+gate) and PRE-SCALED by the activation log2-constant, so the
// 16x16x32 MFMA C-fragment hands each lane all 4 gates of one (unit,chain):
// cell update is lane-local (no DPP, no cross-lane). GEMM (arg-swapped: A=W',
// B=activations, C^T) writes G pre-acts directly in MFMA-fragment order; scan
// loads 32B/lane/step, prefetched 4 steps deep. h exchanged via double-buffered
// LDS (272B pitch -> uniform bank load, 16B-aligned b128 frags), 1 barrier/step.

typedef _Float16 f16;
typedef _Float16 f16x4 __attribute__((ext_vector_type(4)));
typedef _Float16 f16x8 __attribute__((ext_vector_type(8)));
typedef float f32x4 __attribute__((ext_vector_type(4)));

#if defined(__has_builtin)
#if __has_builtin(__builtin_amdgcn_rcpf)
#define FRCP(x) __builtin_amdgcn_rcpf(x)
#else
#define FRCP(x) (1.f / (x))
#endif
#if __has_builtin(__builtin_amdgcn_exp2f)
#define FEXP2(x) __builtin_amdgcn_exp2f(x)
#else
#define FEXP2(x) __exp2f(x)
#endif
#endif

#define K_SIG 1.4426950409f
#define K_TANH 2.8853900818f

static __device__ __forceinline__ f16x8 mk8(uint32_t x, uint32_t y, uint32_t z, uint32_t w) {
    uint4 u; u.x = x; u.y = y; u.z = z; u.w = w;
    return __builtin_bit_cast(f16x8, u);
}

// ---------------- conversions ----------------

__global__ __launch_bounds__(256) void k_convert_x(const float* __restrict__ x,
                                                   f16* __restrict__ xh) {
    size_t id = (size_t)blockIdx.x * 256 + threadIdx.x;  // 4,194,304 threads x 8 elems
    const float4* src = (const float4*)(x + id * 8);
    float4 v0 = src[0], v1 = src[1];
    f16x8 o = {(f16)v0.x, (f16)v0.y, (f16)v0.z, (f16)v0.w,
               (f16)v1.x, (f16)v1.y, (f16)v1.z, (f16)v1.w};
    *(f16x8*)(xh + id * 8) = o;
}

// Permute rows gate-major -> unit-major-gate-minor and scale by activation
// log2 constant. rp = permuted row (0..1023): d=rp>>9, unit=(rp>>2)&127,
// gate=rp&3; orig row = d*512 + gate*128 + unit. K = 8<<ksh.
__global__ __launch_bounds__(256) void k_convert_wp(const float* __restrict__ src,
                                                    f16* __restrict__ dst, int ksh, int n8) {
    int id = blockIdx.x * 256 + threadIdx.x;
    if (id >= n8) return;
    int rp = id >> ksh;
    int kb = id & ((1 << ksh) - 1);
    int dd = rp >> 9, gi = rp & 3, q = (rp >> 2) & 127;
    float sc = (gi == 2) ? K_TANH : K_SIG;
    size_t so = ((size_t)(dd * 512 + gi * 128 + q) << (ksh + 3)) + kb * 8;
    const float4* sp = (const float4*)(src + so);
    float4 v0 = sp[0], v1 = sp[1];
    f16x8 o = {(f16)(v0.x * sc), (f16)(v0.y * sc), (f16)(v0.z * sc), (f16)(v0.w * sc),
               (f16)(v1.x * sc), (f16)(v1.y * sc), (f16)(v1.z * sc), (f16)(v1.w * sc)};
    *(f16x8*)(dst + (size_t)id * 8) = o;
}

__global__ __launch_bounds__(256) void k_bias(const float* __restrict__ a,
                                              const float* __restrict__ b,
                                              float* __restrict__ o) {
    int rp = blockIdx.x * 256 + threadIdx.x;   // 1024
    int dd = rp >> 9, gi = rp & 3, q = (rp >> 2) & 127;
    int orig = dd * 512 + gi * 128 + q;
    float sc = (gi == 2) ? K_TANH : K_SIG;
    o[rp] = (a[orig] + b[orig]) * sc;
}

// ---------------- MFMA GEMM: C^T = A(W' rows) x B(acts)^T, scan-frag output --
// A = W' [1024][256] (permuted+scaled rows), B = acts [131072][256].
// acc[i][j][reg]: permuted row r' = m0+wm+i*16+crow+reg, col cm = b*2048+s.
// Output granule (32B) per (s, wg, wave, lane): [tau 0..3][gate 0..3] f16.

#define BM 128
#define BN 128
#define BKK 32
#define LDT 40   // padded LDS row stride (fp16 elems)

__global__ __launch_bounds__(256) void k_gemm(const f16* __restrict__ A,
                                              const f16* __restrict__ B,
                                              f16* __restrict__ C,
                                              const float* __restrict__ bsum,
                                              int M, int N, int K) {
    __shared__ __align__(16) f16 As[BM * LDT];
    __shared__ __align__(16) f16 Bs[BN * LDT];
    const int tid  = threadIdx.x;
    const int m0   = blockIdx.x * BM;
    const int n0   = blockIdx.y * BN;
    const int lane = tid & 63;
    const int wave = tid >> 6;
    const int wm   = (wave & 1) * 64;
    const int wn   = (wave >> 1) * 64;
    const int r    = tid >> 1;
    const int koff = (tid & 1) * 16;
    const int mrow = lane & 15;
    const int kof  = (lane >> 4) * 8;
    const int crow = (lane >> 4) * 4;

    f32x4 acc[4][4];
#pragma unroll
    for (int i = 0; i < 4; ++i)
#pragma unroll
        for (int j = 0; j < 4; ++j) acc[i][j] = (f32x4){0.f, 0.f, 0.f, 0.f};

    for (int k0 = 0; k0 < K; k0 += BKK) {
        uint4 a0 = *(const uint4*)(A + (size_t)(m0 + r) * K + k0 + koff);
        uint4 a1 = *(const uint4*)(A + (size_t)(m0 + r) * K + k0 + koff + 8);
        uint4 b0 = *(const uint4*)(B + (size_t)(n0 + r) * K + k0 + koff);
        uint4 b1 = *(const uint4*)(B + (size_t)(n0 + r) * K + k0 + koff + 8);
        *(uint4*)(As + r * LDT + koff)     = a0;
        *(uint4*)(As + r * LDT + koff + 8) = a1;
        *(uint4*)(Bs + r * LDT + koff)     = b0;
        *(uint4*)(Bs + r * LDT + koff + 8) = b1;
        __syncthreads();
        f16x8 af[4], bfr[4];
#pragma unroll
        for (int i = 0; i < 4; ++i)
            af[i] = *(const f16x8*)(As + (wm + i * 16 + mrow) * LDT + kof);
#pragma unroll
        for (int j = 0; j < 4; ++j)
            bfr[j] = *(const f16x8*)(Bs + (wn + j * 16 + mrow) * LDT + kof);
#pragma unroll
        for (int i = 0; i < 4; ++i)
#pragma unroll
            for (int j = 0; j < 4; ++j)
                acc[i][j] = __builtin_amdgcn_mfma_f32_16x16x32_f16(af[i], bfr[j], acc[i][j], 0, 0, 0);
        __syncthreads();
    }
#pragma unroll
    for (int i = 0; i < 4; ++i) {
        const int rb = m0 + wm + i * 16 + crow;          // 4-aligned permuted row
        const float4 bbv = *(const float4*)(bsum + rb);  // bias for gates 0..3
        const int dd  = rb >> 9;
        const int rho = rb & 511;
        const int tb  = rho >> 4;
        const int wvv = tb >> 2;
        const int tau = tb & 3;
        const int hii = (rho >> 2) & 3;
#pragma unroll
        for (int j = 0; j < 4; ++j) {
            const int cm = n0 + wn + j * 16 + (lane & 15);
            const int b  = cm >> 11;          // batch
            const int s  = cm & 2047;         // step
            const int gw = dd * 4 + (b >> 4); // scan WG
            const int ch = b & 15;
            const int ln = hii * 16 + ch;
            size_t addr = (size_t)s * 131072 +
                          (size_t)(gw * 16384 + wvv * 2048 + ln * 32 + tau * 8);
            f16x4 v = {(f16)(acc[i][j][0] + bbv.x), (f16)(acc[i][j][1] + bbv.y),
                       (f16)(acc[i][j][2] + bbv.z), (f16)(acc[i][j][3] + bbv.w)};
            *(f16x4*)((char*)C + addr) = v;
        }
    }
}

// ---------------- recurrent LSTM scan (MFMA) ----------------
// WG g: dir = g>>2, batches (g&3)*16..+15. Wave wv owns tiles 4wv..4wv+3
// (tile = 16 permuted rows = 4 units x 4 gates). Lane l: hi=l>>4, ch=l&15.
// Per step: 4x ds_read_b128 h-frags -> 16 MFMA (C-init = G frag) -> lane-local
// activation+cell for 4 (unit,chain) -> 4x ds_write_b16 h -> barrier.
// G granule 32B/lane/step, prefetched 4 deep. MODE 1: stream tout; 2: hfin.

template <int MODE>
__global__ void __attribute__((amdgpu_flat_work_group_size(512, 512))) k_lstm(
    const f16* __restrict__ G,              // scan-frag layout, 268 MB
    const f16* __restrict__ Whh,            // [1024][128] permuted+scaled
    f16* __restrict__ tout,                 // [131072][256] (MODE 1)
    float* __restrict__ hfin,               // [64][256] f32 (MODE 2)
    const int S) {
    const int g  = blockIdx.x;              // 8
    const int d  = g >> 2, bb = g & 3;
    const int t  = threadIdx.x;
    const int l  = t & 63, wv = t >> 6;
    const int hi = l >> 4, ch = l & 15;

    __shared__ __align__(16) char hx[16384];   // 2 bufs x (16 ch x 272B), XOR 8192

    // resident A-frags: w[tau][ks*4+i] = Whh' row (4wv+tau)*16+ch, k ks*32+hi*8
    uint32_t w[4][16];
#pragma unroll
    for (int tau = 0; tau < 4; ++tau) {
        const f16* wr = Whh + (size_t)(d * 512 + (4 * wv + tau) * 16 + ch) * 128 + hi * 8;
#pragma unroll
        for (int ks = 0; ks < 4; ++ks) {
            uint4 q = *(const uint4*)(wr + ks * 32);
            w[tau][ks * 4 + 0] = q.x; w[tau][ks * 4 + 1] = q.y;
            w[tau][ks * 4 + 2] = q.z; w[tau][ks * 4 + 3] = q.w;
        }
    }
#pragma unroll
    for (int tau = 0; tau < 4; ++tau)
#pragma unroll
        for (int i = 0; i < 16; ++i) __asm__("" : "+v"(w[tau][i]));

    for (int i = t; i < 4096; i += 512) ((uint32_t*)hx)[i] = 0;   // h(-1)=0 both bufs

    const int lds_rd = ch * 272 + hi * 16;            // + ks*64 imm
    const int lds_wr = ch * 272 + 32 * wv + 2 * hi;   // + tau*8 imm
    const int lds_f  = (t >> 5) * 272 + (t & 31) * 8; // flush: 8B per thread

    f16* tbase = nullptr;
    if (MODE == 1)
        tbase = tout + ((size_t)(bb * 16 + (t >> 5)) * 2048) * 256 + d * 128 + (t & 31) * 4;

    const char* gp = (const char*)G + (size_t)(g * 16384 + wv * 2048 + l * 32);
    uint4 qa[4], qb[4];
#pragma unroll
    for (int j = 0; j < 4; ++j) {
        qa[j] = *(const uint4*)(gp + (size_t)j * 131072);
        qb[j] = *(const uint4*)(gp + (size_t)j * 131072 + 16);
    }

    float c0 = 0.f, c1 = 0.f, c2 = 0.f, c3 = 0.f;
    int pofs = 0;
    __syncthreads();

    for (int sb = 0; sb < S; sb += 4) {
#pragma unroll
        for (int j = 0; j < 4; ++j) {
            const int s = sb + j;
            if (MODE == 1 && s > 0) {        // stream h(s-1) -> tout (off-path)
                const char* fp = hx + (pofs + lds_f);
                uint2 hv;
                hv.x = *(const uint32_t*)fp;
                hv.y = *(const uint32_t*)(fp + 4);
                *(uint2*)(tbase + (size_t)(s - 1) * 256) = hv;
            }
            const char* hb = hx + (pofs + lds_rd);
            f16x8 b0 = *(const f16x8*)(hb);
            f16x8 b1 = *(const f16x8*)(hb + 64);
            f16x8 b2 = *(const f16x8*)(hb + 128);
            f16x8 b3 = *(const f16x8*)(hb + 192);
            // acc init = G pre-acts (bias + x-part, pre-scaled)
            f16x8 ga = __builtin_bit_cast(f16x8, qa[j]);
            f16x8 gb = __builtin_bit_cast(f16x8, qb[j]);
            f32x4 A0 = {(float)ga[0], (float)ga[1], (float)ga[2], (float)ga[3]};
            f32x4 A1 = {(float)ga[4], (float)ga[5], (float)ga[6], (float)ga[7]};
            f32x4 A2 = {(float)gb[0], (float)gb[1], (float)gb[2], (float)gb[3]};
            f32x4 A3 = {(float)gb[4], (float)gb[5], (float)gb[6], (float)gb[7]};
            {   // prefetch G for step s+4 (stays in flight across barriers)
                int sn = s + 4; if (sn > S - 1) sn = S - 1;
                qa[j] = *(const uint4*)(gp + (size_t)sn * 131072);
                qb[j] = *(const uint4*)(gp + (size_t)sn * 131072 + 16);
            }
            A0 = __builtin_amdgcn_mfma_f32_16x16x32_f16(mk8(w[0][0], w[0][1], w[0][2], w[0][3]), b0, A0, 0, 0, 0);
            A1 = __builtin_amdgcn_mfma_f32_16x16x32_f16(mk8(w[1][0], w[1][1], w[1][2], w[1][3]), b0, A1, 0, 0, 0);
            A2 = __builtin_amdgcn_mfma_f32_16x16x32_f16(mk8(w[2][0], w[2][1], w[2][2], w[2][3]), b0, A2, 0, 0, 0);
            A3 = __builtin_amdgcn_mfma_f32_16x16x32_f16(mk8(w[3][0], w[3][1], w[3][2], w[3][3]), b0, A3, 0, 0, 0);
            A0 = __builtin_amdgcn_mfma_f32_16x16x32_f16(mk8(w[0][4], w[0][5], w[0][6], w[0][7]), b1, A0, 0, 0, 0);
            A1 = __builtin_amdgcn_mfma_f32_16x16x32_f16(mk8(w[1][4], w[1][5], w[1][6], w[1][7]), b1, A1, 0, 0, 0);
            A2 = __builtin_amdgcn_mfma_f32_16x16x32_f16(mk8(w[2][4], w[2][5], w[2][6], w[2][7]), b1, A2, 0, 0, 0);
            A3 = __builtin_amdgcn_mfma_f32_16x16x32_f16(mk8(w[3][4], w[3][5], w[3][6], w[3][7]), b1, A3, 0, 0, 0);
            A0 = __builtin_amdgcn_mfma_f32_16x16x32_f16(mk8(w[0][8], w[0][9], w[0][10], w[0][11]), b2, A0, 0, 0, 0);
            A1 = __builtin_amdgcn_mfma_f32_16x16x32_f16(mk8(w[1][8], w[1][9], w[1][10], w[1][11]), b2, A1, 0, 0, 0);
            A2 = __builtin_amdgcn_mfma_f32_16x16x32_f16(mk8(w[2][8], w[2][9], w[2][10], w[2][11]), b2, A2, 0, 0, 0);
            A3 = __builtin_amdgcn_mfma_f32_16x16x32_f16(mk8(w[3][8], w[3][9], w[3][10], w[3][11]), b2, A3, 0, 0, 0);
            A0 = __builtin_amdgcn_mfma_f32_16x16x32_f16(mk8(w[0][12], w[0][13], w[0][14], w[0][15]), b3, A0, 0, 0, 0);
            A1 = __builtin_amdgcn_mfma_f32_16x16x32_f16(mk8(w[1][12], w[1][13], w[1][14], w[1][15]), b3, A1, 0, 0, 0);
            A2 = __builtin_amdgcn_mfma_f32_16x16x32_f16(mk8(w[2][12], w[2][13], w[2][14], w[2][15]), b3, A2, 0, 0, 0);
            A3 = __builtin_amdgcn_mfma_f32_16x16x32_f16(mk8(w[3][12], w[3][13], w[3][14], w[3][15]), b3, A3, 0, 0, 0);
            // lane-local activation + cell (pre-acts already scaled by log2 k)
            float h0, h1, h2, h3;
            {
                float si = FRCP(1.f + FEXP2(-A0[0]));
                float sf = FRCP(1.f + FEXP2(-A0[1]));
                float tg = __builtin_fmaf(-2.f, FRCP(1.f + FEXP2(A0[2])), 1.f);
                float so = FRCP(1.f + FEXP2(-A0[3]));
                c0 = __builtin_fmaf(sf, c0, si * tg);
                float tc = __builtin_fmaf(-2.f, FRCP(1.f + FEXP2(c0 * K_TANH)), 1.f);
                h0 = so * tc;
            }
            {
                float si = FRCP(1.f + FEXP2(-A1[0]));
                float sf = FRCP(1.f + FEXP2(-A1[1]));
                float tg = __builtin_fmaf(-2.f, FRCP(1.f + FEXP2(A1[2])), 1.f);
                float so = FRCP(1.f + FEXP2(-A1[3]));
                c1 = __builtin_fmaf(sf, c1, si * tg);
                float tc = __builtin_fmaf(-2.f, FRCP(1.f + FEXP2(c1 * K_TANH)), 1.f);
                h1 = so * tc;
            }
            {
                float si = FRCP(1.f + FEXP2(-A2[0]));
                float sf = FRCP(1.f + FEXP2(-A2[1]));
                float tg = __builtin_fmaf(-2.f, FRCP(1.f + FEXP2(A2[2])), 1.f);
                float so = FRCP(1.f + FEXP2(-A2[3]));
                c2 = __builtin_fmaf(sf, c2, si * tg);
                float tc = __builtin_fmaf(-2.f, FRCP(1.f + FEXP2(c2 * K_TANH)), 1.f);
                h2 = so * tc;
            }
            {
                float si = FRCP(1.f + FEXP2(-A3[0]));
                float sf = FRCP(1.f + FEXP2(-A3[1]));
                float tg = __builtin_fmaf(-2.f, FRCP(1.f + FEXP2(A3[2])), 1.f);
                float so = FRCP(1.f + FEXP2(-A3[3]));
                c3 = __builtin_fmaf(sf, c3, si * tg);
                float tc = __builtin_fmaf(-2.f, FRCP(1.f + FEXP2(c3 * K_TANH)), 1.f);
                h3 = so * tc;
            }
            if (MODE == 2 && s == S - 1) {   // final pitch h, f32 (once)
                float* hf = hfin + (size_t)(bb * 16 + ch) * 256 + d * 128 + 16 * wv + hi;
                hf[0] = h0; hf[4] = h1; hf[8] = h2; hf[12] = h3;
            }
            char* hw = hx + ((pofs ^ 8192) + lds_wr);
            *(f16*)(hw)      = (f16)h0;
            *(f16*)(hw + 8)  = (f16)h1;
            *(f16*)(hw + 16) = (f16)h2;
            *(f16*)(hw + 24) = (f16)h3;
            // LDS-only drain + barrier: G prefetch stays in flight
            __asm__ __volatile__("s_waitcnt lgkmcnt(0)\n\ts_barrier" ::: "memory");
            pofs ^= 8192;
        }
    }
    if (MODE == 1) {                         // flush h(S-1) (in buf 0 after even S)
        const char* fp = hx + lds_f;
        uint2 hv;
        hv.x = *(const uint32_t*)fp;
        hv.y = *(const uint32_t*)(fp + 4);
        *(uint2*)(tbase + (size_t)(S - 1) * 256) = hv;
    }
}

// ---------------- output projection ----------------

__global__ __launch_bounds__(128) void k_out(const float* __restrict__ hp,  // [64][256]
                                             const float* __restrict__ Wo,  // [88][256]
                                             const float* __restrict__ bo,  // [88]
                                             float* __restrict__ out) {     // [64][88]
    const int b = blockIdx.x;
    const int t = threadIdx.x;
    __shared__ float hs[256];
    hs[t] = hp[b * 256 + t];
    hs[t + 128] = hp[b * 256 + 128 + t];
    __syncthreads();
    if (t < 88) {
        float acc = bo[t];
        const float* wr = Wo + t * 256;
#pragma unroll 4
        for (int k = 0; k < 256; ++k) acc += wr[k] * hs[k];
        out[b * 88 + t] = acc;
    }
}

// ---------------- launch ----------------

extern "C" void kernel_launch(void* const* d_in, const int* in_sizes, int n_in,
                              void* d_out, int out_size, void* d_ws, size_t ws_size,
                              hipStream_t stream) {
    const float* x    = (const float*)d_in[0];
    const float* Wtih = (const float*)d_in[1];
    const float* Wthh = (const float*)d_in[2];
    const float* btih = (const float*)d_in[3];
    const float* bthh = (const float*)d_in[4];
    const float* Wpih = (const float*)d_in[5];
    const float* Wphh = (const float*)d_in[6];
    const float* bpih = (const float*)d_in[7];
    const float* bphh = (const float*)d_in[8];
    const float* Wo   = (const float*)d_in[9];
    const float* bo   = (const float*)d_in[10];

    char* ws = (char*)d_ws;
    f16*   xh    = (f16*)(ws + 0);            //  67,108,864 B  [131072][256]
    f16*   G     = (f16*)(ws + 67108864);     // 268,435,456 B  scan-frag layout
    f16*   tout  = (f16*)(ws + 335544320);    //  67,108,864 B  [131072][256]
    f16*   wtih  = (f16*)(ws + 402653184);    //     524,288 B  permuted+scaled
    f16*   wthh  = (f16*)(ws + 403177472);    //     262,144 B
    f16*   wpih  = (f16*)(ws + 403439616);    //     524,288 B
    f16*   wphh  = (f16*)(ws + 403963904);    //     262,144 B
    // hp region reused: biases live here during GEMMs, hfin overwrites after
    float* bsT   = (float*)(ws + 404226048);  //       4,096 B
    float* bsP   = (float*)(ws + 404230144);  //       4,096 B
    float* hp    = (float*)(ws + 404226048);  //      65,536 B  (written by scan2)

    k_convert_x<<<16384, 256, 0, stream>>>(x, xh);
    k_convert_wp<<<128, 256, 0, stream>>>(Wtih, wtih, 5, 32768);
    k_convert_wp<<<64,  256, 0, stream>>>(Wthh, wthh, 4, 16384);
    k_convert_wp<<<128, 256, 0, stream>>>(Wpih, wpih, 5, 32768);
    k_convert_wp<<<64,  256, 0, stream>>>(Wphh, wphh, 4, 16384);
    k_bias<<<4, 256, 0, stream>>>(btih, bthh, bsT);
    k_bias<<<4, 256, 0, stream>>>(bpih, bphh, bsP);

    // G = (xh @ Wt_ih'^T)^T + bias, scan-frag layout
    k_gemm<<<dim3(8, 1024), 256, 0, stream>>>(wtih, xh, G, bsT, 1024, 131072, 256);
    // time-level scan -> tout
    k_lstm<1><<<8, 512, 0, stream>>>(G, wthh, tout, nullptr, 2048);
    // G = (tout @ Wp_ih'^T)^T + bias
    k_gemm<<<dim3(8, 1024), 256, 0, stream>>>(wpih, tout, G, bsP, 1024, 131072, 256);
    // pitch-level scan -> final h (f32, overwrites bias region)
    k_lstm<2><<<8, 512, 0, stream>>>(G, wphh, nullptr, hp, 2048);
    // output projection
    k_out<<<64, 128, 0, stream>>>(hp, Wo, bo, (float*)d_out);
}

// Round 4
// 2388.459 us; speedup vs baseline: 1.8274x; 1.6872x over previous
//
#include <hip/hip_runtime.h>
#include <hip/hip_fp16.h>
#include <stdint.h>

// MDRNN: 2-level bidirectional LSTM, S=2048 steps, B=64, H=128, I=256, O=88.
// Scan v10: MFMA recurrence at v5's parallelism. 128 WGs (one per (batch,dir)
// chain) x 512 thr. B-operand = h broadcast into all 16 MFMA columns -> every
// lane's C-frag holds valid gates (unit=tile*4+hi, gates=regs); lane (hi,ch)
// activates only tile tau*=ch&3 (2-level cndmask select) so activation work is
// 10 trans-instr/wave-step with all lanes useful. No DPP reduce (MFMA sums K).
// Weights resident as f16x8 (no decompose->no per-step movs). G pre-acts in
// [b][s/8][d][u][s%8][g] layout: GEMM stores coalesce into 64B runs AND the
// scan loads 64B/thread per 8-step block (4x dwordx4, prefetched 1 block).
// h via 16-slot LDS ring: broadcast reads (conflict-free), doubles as tout
// history flushed per 8-step block.

typedef _Float16 f16;
typedef _Float16 f16x4 __attribute__((ext_vector_type(4)));
typedef _Float16 f16x8 __attribute__((ext_vector_type(8)));
typedef float f32x4 __attribute__((ext_vector_type(4)));

#if defined(__has_builtin)
#if __has_builtin(__builtin_amdgcn_rcpf)
#define FRCP(x) __builtin_amdgcn_rcpf(x)
#else
#define FRCP(x) (1.f / (x))
#endif
#if __has_builtin(__builtin_amdgcn_exp2f)
#define FEXP2(x) __builtin_amdgcn_exp2f(x)
#else
#define FEXP2(x) __exp2f(x)
#endif
#endif

#define K_SIG 1.4426950409f
#define K_TANH 2.8853900818f

// ---------------- conversions ----------------

__global__ __launch_bounds__(256) void k_convert_x(const float* __restrict__ x,
                                                   f16* __restrict__ xh) {
    size_t id = (size_t)blockIdx.x * 256 + threadIdx.x;  // 4,194,304 threads x 8 elems
    const float4* src = (const float4*)(x + id * 8);
    float4 v0 = src[0], v1 = src[1];
    f16x8 o = {(f16)v0.x, (f16)v0.y, (f16)v0.z, (f16)v0.w,
               (f16)v1.x, (f16)v1.y, (f16)v1.z, (f16)v1.w};
    *(f16x8*)(xh + id * 8) = o;
}

// Permute rows gate-major -> unit-major-gate-minor and scale by activation
// log2 constant. rp = permuted row (0..1023): d=rp>>9, unit=(rp>>2)&127,
// gate=rp&3; orig row = d*512 + gate*128 + unit. K = 8<<ksh.
__global__ __launch_bounds__(256) void k_convert_wp(const float* __restrict__ src,
                                                    f16* __restrict__ dst, int ksh, int n8) {
    int id = blockIdx.x * 256 + threadIdx.x;
    if (id >= n8) return;
    int rp = id >> ksh;
    int kb = id & ((1 << ksh) - 1);
    int dd = rp >> 9, gi = rp & 3, q = (rp >> 2) & 127;
    float sc = (gi == 2) ? K_TANH : K_SIG;
    size_t so = ((size_t)(dd * 512 + gi * 128 + q) << (ksh + 3)) + kb * 8;
    const float4* sp = (const float4*)(src + so);
    float4 v0 = sp[0], v1 = sp[1];
    f16x8 o = {(f16)(v0.x * sc), (f16)(v0.y * sc), (f16)(v0.z * sc), (f16)(v0.w * sc),
               (f16)(v1.x * sc), (f16)(v1.y * sc), (f16)(v1.z * sc), (f16)(v1.w * sc)};
    *(f16x8*)(dst + (size_t)id * 8) = o;
}

__global__ __launch_bounds__(256) void k_bias(const float* __restrict__ a,
                                              const float* __restrict__ b,
                                              float* __restrict__ o) {
    int rp = blockIdx.x * 256 + threadIdx.x;   // 1024
    int dd = rp >> 9, gi = rp & 3, q = (rp >> 2) & 127;
    int orig = dd * 512 + gi * 128 + q;
    float sc = (gi == 2) ? K_TANH : K_SIG;
    o[rp] = (a[orig] + b[orig]) * sc;
}

// ---------------- MFMA GEMM: C = A(W' rows) x B(acts)^T, scan-block output ---
// A = W' [1024][256] (permuted+scaled rows), B = acts [131072][256].
// acc[i][j][reg]: permuted row r' = rb+reg (one unit, 4 gates), col cm = b*2048+s.
// G layout: [b][s>>3][d][u][s&7][gate] f16 -> f16x4 stores, 64B-coalesced runs;
// scan reads 64B per (thread, 8-step block).

#define BM 128
#define BN 128
#define BKK 32
#define LDT 40   // padded LDS row stride (fp16 elems)

__global__ __launch_bounds__(256) void k_gemm(const f16* __restrict__ A,
                                              const f16* __restrict__ B,
                                              f16* __restrict__ C,
                                              const float* __restrict__ bsum,
                                              int M, int N, int K) {
    __shared__ __align__(16) f16 As[BM * LDT];
    __shared__ __align__(16) f16 Bs[BN * LDT];
    const int tid  = threadIdx.x;
    const int m0   = blockIdx.x * BM;
    const int n0   = blockIdx.y * BN;
    const int lane = tid & 63;
    const int wave = tid >> 6;
    const int wm   = (wave & 1) * 64;
    const int wn   = (wave >> 1) * 64;
    const int r    = tid >> 1;
    const int koff = (tid & 1) * 16;
    const int mrow = lane & 15;
    const int kof  = (lane >> 4) * 8;
    const int crow = (lane >> 4) * 4;

    f32x4 acc[4][4];
#pragma unroll
    for (int i = 0; i < 4; ++i)
#pragma unroll
        for (int j = 0; j < 4; ++j) acc[i][j] = (f32x4){0.f, 0.f, 0.f, 0.f};

    for (int k0 = 0; k0 < K; k0 += BKK) {
        uint4 a0 = *(const uint4*)(A + (size_t)(m0 + r) * K + k0 + koff);
        uint4 a1 = *(const uint4*)(A + (size_t)(m0 + r) * K + k0 + koff + 8);
        uint4 b0 = *(const uint4*)(B + (size_t)(n0 + r) * K + k0 + koff);
        uint4 b1 = *(const uint4*)(B + (size_t)(n0 + r) * K + k0 + koff + 8);
        *(uint4*)(As + r * LDT + koff)     = a0;
        *(uint4*)(As + r * LDT + koff + 8) = a1;
        *(uint4*)(Bs + r * LDT + koff)     = b0;
        *(uint4*)(Bs + r * LDT + koff + 8) = b1;
        __syncthreads();
        f16x8 af[4], bfr[4];
#pragma unroll
        for (int i = 0; i < 4; ++i)
            af[i] = *(const f16x8*)(As + (wm + i * 16 + mrow) * LDT + kof);
#pragma unroll
        for (int j = 0; j < 4; ++j)
            bfr[j] = *(const f16x8*)(Bs + (wn + j * 16 + mrow) * LDT + kof);
#pragma unroll
        for (int i = 0; i < 4; ++i)
#pragma unroll
            for (int j = 0; j < 4; ++j)
                acc[i][j] = __builtin_amdgcn_mfma_f32_16x16x32_f16(af[i], bfr[j], acc[i][j], 0, 0, 0);
        __syncthreads();
    }
#pragma unroll
    for (int i = 0; i < 4; ++i) {
        const int rb = m0 + wm + i * 16 + crow;          // 4-aligned permuted row
        const float4 bbv = *(const float4*)(bsum + rb);  // bias for gates 0..3
        const int dd = rb >> 9;
        const int uu = (rb & 511) >> 2;                  // unit 0..127
#pragma unroll
        for (int j = 0; j < 4; ++j) {
            const int cm = n0 + wn + j * 16 + (lane & 15);
            const int b  = cm >> 11;          // batch
            const int s  = cm & 2047;         // step
            f16x4 v = {(f16)(acc[i][j][0] + bbv.x), (f16)(acc[i][j][1] + bbv.y),
                       (f16)(acc[i][j][2] + bbv.z), (f16)(acc[i][j][3] + bbv.w)};
            size_t fofs = ((((size_t)b * 256 + (s >> 3)) * 2 + dd) * 128 + uu) * 32
                          + (s & 7) * 4;
            *(f16x4*)(C + fofs) = v;
        }
    }
}

// ---------------- recurrent LSTM scan (MFMA, 1 chain/WG) ----------------
// WG = (batch b, dir d). 8 waves x 4 tiles (tile = 4 units x 4 gates). B = h
// broadcast to all 16 cols: lane (hi,ch) gets gates of unit (4wv+tau)*4+hi for
// each tau in its 4 accs; it activates tau*=ch&3 only (cndmask select), so all
// 64 lanes do useful activation work (10 trans/wave-step). h: 16-slot LDS ring,
// broadcast b128 reads, 16-lane writes. MODE 1: stream tout; MODE 2: hfin.

template <int MODE>
__global__ void __attribute__((amdgpu_flat_work_group_size(512, 512),
                               amdgpu_waves_per_eu(2, 2))) k_lstm(
    const f16* __restrict__ G,              // [b][s/8][d][u][s%8][g] f16
    const f16* __restrict__ Whh,            // [1024][128] permuted+scaled
    f16* __restrict__ tout,                 // [131072][256] (MODE 1)
    float* __restrict__ hfin,               // [64][256] f32 (MODE 2)
    const int S) {
    const int wg = blockIdx.x;              // 128
    const int b  = wg >> 1, d = wg & 1;
    const int t  = threadIdx.x;
    const int l  = t & 63, wv = t >> 6;
    const int hi = l >> 4, ch = l & 15;
    const int tau = ch & 3;

    __shared__ __align__(16) f16 ring[16][128];   // 16 slots x 256B

    // resident A-frags: w[tt][ks] = tile (4wv+tt), rows sub=ch, k = ks*32+hi*8
    f16x8 w[4][4];
#pragma unroll
    for (int tt = 0; tt < 4; ++tt)
#pragma unroll
        for (int ks = 0; ks < 4; ++ks)
            w[tt][ks] = *(const f16x8*)(Whh + ((size_t)d * 512 + (4 * wv + tt) * 16 + ch) * 128
                                        + ks * 32 + hi * 8);

    for (int i = t; i < 1024; i += 512) ((uint32_t*)ring)[i] = 0;  // h(-1)=0

    const int u = 16 * wv + 4 * tau + hi;   // the unit this lane activates
    const f16* gp = G + ((((size_t)b * 256) * 2 + d) * 128 + u) * 32;

    uint4 gc[4], gn[4];                     // 64B G granule: 8 steps x f16x4
#pragma unroll
    for (int q = 0; q < 4; ++q) gc[q] = *(const uint4*)(gp + q * 8);

    const f32x4 Z = {0.f, 0.f, 0.f, 0.f};
    float c = 0.f;
    __syncthreads();

    for (int sb = 0; sb < S; sb += 8) {
        {   // prefetch next block's G granule (in flight across barriers)
            const size_t nb = (size_t)((sb + 8 < S) ? (sb >> 3) + 1 : (sb >> 3));
#pragma unroll
            for (int q = 0; q < 4; ++q) gn[q] = *(const uint4*)(gp + nb * 8192 + q * 8);
        }
        if (MODE == 1 && sb > 0 && t < 256) {   // stream block sb-8 -> tout
            const int jf = t >> 5, of = t & 31;
            uint2 hv = *(const uint2*)(&ring[((sb - 8) & 15) + jf][of * 4]);
            *(uint2*)(tout + ((size_t)b * 2048 + (sb - 8 + jf)) * 256 + d * 128 + of * 4) = hv;
        }
#pragma unroll
        for (int j8 = 0; j8 < 8; ++j8) {
            const int s = sb + j8;
            const f16* hb = &ring[(s + 15) & 15][0];
            f16x8 b0 = *(const f16x8*)(hb + hi * 8);        // broadcast per hi-group
            f16x8 b1 = *(const f16x8*)(hb + 32 + hi * 8);
            f16x8 b2 = *(const f16x8*)(hb + 64 + hi * 8);
            f16x8 b3 = *(const f16x8*)(hb + 96 + hi * 8);
            f32x4 A0 = __builtin_amdgcn_mfma_f32_16x16x32_f16(w[0][0], b0, Z, 0, 0, 0);
            f32x4 A1 = __builtin_amdgcn_mfma_f32_16x16x32_f16(w[1][0], b0, Z, 0, 0, 0);
            f32x4 A2 = __builtin_amdgcn_mfma_f32_16x16x32_f16(w[2][0], b0, Z, 0, 0, 0);
            f32x4 A3 = __builtin_amdgcn_mfma_f32_16x16x32_f16(w[3][0], b0, Z, 0, 0, 0);
            A0 = __builtin_amdgcn_mfma_f32_16x16x32_f16(w[0][1], b1, A0, 0, 0, 0);
            A1 = __builtin_amdgcn_mfma_f32_16x16x32_f16(w[1][1], b1, A1, 0, 0, 0);
            A2 = __builtin_amdgcn_mfma_f32_16x16x32_f16(w[2][1], b1, A2, 0, 0, 0);
            A3 = __builtin_amdgcn_mfma_f32_16x16x32_f16(w[3][1], b1, A3, 0, 0, 0);
            A0 = __builtin_amdgcn_mfma_f32_16x16x32_f16(w[0][2], b2, A0, 0, 0, 0);
            A1 = __builtin_amdgcn_mfma_f32_16x16x32_f16(w[1][2], b2, A1, 0, 0, 0);
            A2 = __builtin_amdgcn_mfma_f32_16x16x32_f16(w[2][2], b2, A2, 0, 0, 0);
            A3 = __builtin_amdgcn_mfma_f32_16x16x32_f16(w[3][2], b2, A3, 0, 0, 0);
            A0 = __builtin_amdgcn_mfma_f32_16x16x32_f16(w[0][3], b3, A0, 0, 0, 0);
            A1 = __builtin_amdgcn_mfma_f32_16x16x32_f16(w[1][3], b3, A1, 0, 0, 0);
            A2 = __builtin_amdgcn_mfma_f32_16x16x32_f16(w[2][3], b3, A2, 0, 0, 0);
            A3 = __builtin_amdgcn_mfma_f32_16x16x32_f16(w[3][3], b3, A3, 0, 0, 0);
            // select acc tau* = ch&3 (2-level cndmask) + add G pre-acts
            uint2 gpair;
            if ((j8 & 1) == 0) { gpair.x = gc[j8 >> 1].x; gpair.y = gc[j8 >> 1].y; }
            else               { gpair.x = gc[j8 >> 1].z; gpair.y = gc[j8 >> 1].w; }
            f16x4 gf = __builtin_bit_cast(f16x4, gpair);
            const bool s0 = (ch & 1) != 0;
            const bool s1 = (ch & 2) != 0;
            float v0, v1, v2, v3;
            {
                float x, y;
                x = s0 ? A1[0] : A0[0]; y = s0 ? A3[0] : A2[0]; v0 = (s1 ? y : x) + (float)gf[0];
                x = s0 ? A1[1] : A0[1]; y = s0 ? A3[1] : A2[1]; v1 = (s1 ? y : x) + (float)gf[1];
                x = s0 ? A1[2] : A0[2]; y = s0 ? A3[2] : A2[2]; v2 = (s1 ? y : x) + (float)gf[2];
                x = s0 ? A1[3] : A0[3]; y = s0 ? A3[3] : A2[3]; v3 = (s1 ? y : x) + (float)gf[3];
            }
            // activation (pre-scaled by log2 consts): i,f,o sigmoid; g tanh
            float si = FRCP(1.f + FEXP2(-v0));
            float sf = FRCP(1.f + FEXP2(-v1));
            float tg = __builtin_fmaf(-2.f, FRCP(1.f + FEXP2(v2)), 1.f);
            float so = FRCP(1.f + FEXP2(-v3));
            c = __builtin_fmaf(sf, c, si * tg);
            float tc = __builtin_fmaf(-2.f, FRCP(1.f + FEXP2(c * K_TANH)), 1.f);
            float hv = so * tc;
            if (ch < 4) ring[s & 15][u] = (f16)hv;   // ch==tau* here
            if (MODE == 2 && s == S - 1 && ch < 4)
                hfin[(size_t)b * 256 + d * 128 + u] = hv;
            // LDS-only drain + barrier: G prefetch stays in flight
            __asm__ __volatile__("s_waitcnt lgkmcnt(0)\n\ts_barrier" ::: "memory");
        }
#pragma unroll
        for (int q = 0; q < 4; ++q) gc[q] = gn[q];
    }
    if (MODE == 1 && t < 256) {             // flush final block (steps S-8..S-1)
        const int jf = t >> 5, of = t & 31;
        uint2 hv = *(const uint2*)(&ring[((S - 8) & 15) + jf][of * 4]);
        *(uint2*)(tout + ((size_t)b * 2048 + (S - 8 + jf)) * 256 + d * 128 + of * 4) = hv;
    }
}

// ---------------- output projection ----------------

__global__ __launch_bounds__(128) void k_out(const float* __restrict__ hp,  // [64][256]
                                             const float* __restrict__ Wo,  // [88][256]
                                             const float* __restrict__ bo,  // [88]
                                             float* __restrict__ out) {     // [64][88]
    const int b = blockIdx.x;
    const int t = threadIdx.x;
    __shared__ float hs[256];
    hs[t] = hp[b * 256 + t];
    hs[t + 128] = hp[b * 256 + 128 + t];
    __syncthreads();
    if (t < 88) {
        float acc = bo[t];
        const float* wr = Wo + t * 256;
#pragma unroll 4
        for (int k = 0; k < 256; ++k) acc += wr[k] * hs[k];
        out[b * 88 + t] = acc;
    }
}

// ---------------- launch ----------------

extern "C" void kernel_launch(void* const* d_in, const int* in_sizes, int n_in,
                              void* d_out, int out_size, void* d_ws, size_t ws_size,
                              hipStream_t stream) {
    const float* x    = (const float*)d_in[0];
    const float* Wtih = (const float*)d_in[1];
    const float* Wthh = (const float*)d_in[2];
    const float* btih = (const float*)d_in[3];
    const float* bthh = (const float*)d_in[4];
    const float* Wpih = (const float*)d_in[5];
    const float* Wphh = (const float*)d_in[6];
    const float* bpih = (const float*)d_in[7];
    const float* bphh = (const float*)d_in[8];
    const float* Wo   = (const float*)d_in[9];
    const float* bo   = (const float*)d_in[10];

    char* ws = (char*)d_ws;
    f16*   xh    = (f16*)(ws + 0);            //  67,108,864 B  [131072][256]
    f16*   G     = (f16*)(ws + 67108864);     // 268,435,456 B  scan-block layout
    f16*   tout  = (f16*)(ws + 335544320);    //  67,108,864 B  [131072][256]
    f16*   wtih  = (f16*)(ws + 402653184);    //     524,288 B  permuted+scaled
    f16*   wthh  = (f16*)(ws + 403177472);    //     262,144 B
    f16*   wpih  = (f16*)(ws + 403439616);    //     524,288 B
    f16*   wphh  = (f16*)(ws + 403963904);    //     262,144 B
    float* bsT   = (float*)(ws + 404226048);  //       4,096 B
    float* bsP   = (float*)(ws + 404230144);  //       4,096 B
    float* hp    = (float*)(ws + 404226048);  //      65,536 B  (written by scan2)

    k_convert_x<<<16384, 256, 0, stream>>>(x, xh);
    k_convert_wp<<<128, 256, 0, stream>>>(Wtih, wtih, 5, 32768);
    k_convert_wp<<<64,  256, 0, stream>>>(Wthh, wthh, 4, 16384);
    k_convert_wp<<<128, 256, 0, stream>>>(Wpih, wpih, 5, 32768);
    k_convert_wp<<<64,  256, 0, stream>>>(Wphh, wphh, 4, 16384);
    k_bias<<<4, 256, 0, stream>>>(btih, bthh, bsT);
    k_bias<<<4, 256, 0, stream>>>(bpih, bphh, bsP);

    // G = (xh @ Wt_ih'^T) + bias, scan-block layout
    k_gemm<<<dim3(8, 1024), 256, 0, stream>>>(wtih, xh, G, bsT, 1024, 131072, 256);
    // time-level scan -> tout
    k_lstm<1><<<128, 512, 0, stream>>>(G, wthh, tout, nullptr, 2048);
    // G = (tout @ Wp_ih'^T) + bias
    k_gemm<<<dim3(8, 1024), 256, 0, stream>>>(wpih, tout, G, bsP, 1024, 131072, 256);
    // pitch-level scan -> final h
    k_lstm<2><<<128, 512, 0, stream>>>(G, wphh, nullptr, hp, 2048);
    // output projection
    k_out<<<64, 128, 0, stream>>>(hp, Wo, bo, (float*)d_out);
}

// Round 5
// 2358.745 us; speedup vs baseline: 1.8505x; 1.0126x over previous
//
#include <hip/hip_runtime.h>
#include <hip/hip_fp16.h>
#include <stdint.h>

// MDRNN: 2-level bidirectional LSTM, S=2048 steps, B=64, H=128, I=256, O=88.
// Scan v11: v10's MFMA recurrence (128 WGs, broadcast-B) with a v5-style
// ONE-(unit,gate)-PER-LANE tail: acc tile selected by ch>>2 (quad-uniform),
// C-reg by ch&3 -> quad = 4 gates of one unit. Sigmoid sign pre-folded into
// the weight/bias scaling (-log2e for i,f,o; +2log2e for g) so activation is
// rcp(1+exp2(v)) + fma: 2 trans/lane + 2 for tanh(c) = 4 trans/step (was 10).
// Gates redistributed by 4 DPP quad-broadcasts. Ring addressing via 2 hoisted
// base regs -> all ds offsets immediate. Everything else as v10.

typedef _Float16 f16;
typedef _Float16 f16x4 __attribute__((ext_vector_type(4)));
typedef _Float16 f16x8 __attribute__((ext_vector_type(8)));
typedef float f32x4 __attribute__((ext_vector_type(4)));

#if defined(__has_builtin)
#if __has_builtin(__builtin_amdgcn_rcpf)
#define FRCP(x) __builtin_amdgcn_rcpf(x)
#else
#define FRCP(x) (1.f / (x))
#endif
#if __has_builtin(__builtin_amdgcn_exp2f)
#define FEXP2(x) __builtin_amdgcn_exp2f(x)
#else
#define FEXP2(x) __exp2f(x)
#endif
#endif

#define K_SIG 1.4426950409f
#define K_TANH 2.8853900818f

template <int CTRL>
static __device__ __forceinline__ float qperm(float v) {
    int r = __builtin_amdgcn_update_dpp(0, __builtin_bit_cast(int, v), CTRL, 0xf, 0xf, true);
    return __builtin_bit_cast(float, r);
}

// ---------------- conversions ----------------

__global__ __launch_bounds__(256) void k_convert_x(const float* __restrict__ x,
                                                   f16* __restrict__ xh) {
    size_t id = (size_t)blockIdx.x * 256 + threadIdx.x;  // 4,194,304 threads x 8 elems
    const float4* src = (const float4*)(x + id * 8);
    float4 v0 = src[0], v1 = src[1];
    f16x8 o = {(f16)v0.x, (f16)v0.y, (f16)v0.z, (f16)v0.w,
               (f16)v1.x, (f16)v1.y, (f16)v1.z, (f16)v1.w};
    *(f16x8*)(xh + id * 8) = o;
}

// Permute rows gate-major -> unit-major-gate-minor and scale by the activation
// log2 constant WITH SIGN: gates i,f,o (0,1,3) -> -log2e (sigmoid computed as
// rcp(1+exp2(v))), gate g (2) -> +2log2e (tanh as 1-2*rcp(1+exp2(v))).
// rp = permuted row (0..1023): d=rp>>9, unit=(rp>>2)&127, gate=rp&3;
// orig row = d*512 + gate*128 + unit. K = 8<<ksh.
__global__ __launch_bounds__(256) void k_convert_wp(const float* __restrict__ src,
                                                    f16* __restrict__ dst, int ksh, int n8) {
    int id = blockIdx.x * 256 + threadIdx.x;
    if (id >= n8) return;
    int rp = id >> ksh;
    int kb = id & ((1 << ksh) - 1);
    int dd = rp >> 9, gi = rp & 3, q = (rp >> 2) & 127;
    float sc = (gi == 2) ? K_TANH : -K_SIG;
    size_t so = ((size_t)(dd * 512 + gi * 128 + q) << (ksh + 3)) + kb * 8;
    const float4* sp = (const float4*)(src + so);
    float4 v0 = sp[0], v1 = sp[1];
    f16x8 o = {(f16)(v0.x * sc), (f16)(v0.y * sc), (f16)(v0.z * sc), (f16)(v0.w * sc),
               (f16)(v1.x * sc), (f16)(v1.y * sc), (f16)(v1.z * sc), (f16)(v1.w * sc)};
    *(f16x8*)(dst + (size_t)id * 8) = o;
}

__global__ __launch_bounds__(256) void k_bias(const float* __restrict__ a,
                                              const float* __restrict__ b,
                                              float* __restrict__ o) {
    int rp = blockIdx.x * 256 + threadIdx.x;   // 1024
    int dd = rp >> 9, gi = rp & 3, q = (rp >> 2) & 127;
    int orig = dd * 512 + gi * 128 + q;
    float sc = (gi == 2) ? K_TANH : -K_SIG;
    o[rp] = (a[orig] + b[orig]) * sc;
}

// ---------------- MFMA GEMM: C = A(W' rows) x B(acts)^T, scan-block output ---
// A = W' [1024][256] (permuted+scaled rows), B = acts [131072][256].
// G layout: [b][s>>3][d][u][s&7][gate] f16 -> f16x4 stores, 64B-coalesced runs;
// scan reads 64B per (thread, 8-step block).

#define BM 128
#define BN 128
#define BKK 32
#define LDT 40   // padded LDS row stride (fp16 elems)

__global__ __launch_bounds__(256) void k_gemm(const f16* __restrict__ A,
                                              const f16* __restrict__ B,
                                              f16* __restrict__ C,
                                              const float* __restrict__ bsum,
                                              int M, int N, int K) {
    __shared__ __align__(16) f16 As[BM * LDT];
    __shared__ __align__(16) f16 Bs[BN * LDT];
    const int tid  = threadIdx.x;
    const int m0   = blockIdx.x * BM;
    const int n0   = blockIdx.y * BN;
    const int lane = tid & 63;
    const int wave = tid >> 6;
    const int wm   = (wave & 1) * 64;
    const int wn   = (wave >> 1) * 64;
    const int r    = tid >> 1;
    const int koff = (tid & 1) * 16;
    const int mrow = lane & 15;
    const int kof  = (lane >> 4) * 8;
    const int crow = (lane >> 4) * 4;

    f32x4 acc[4][4];
#pragma unroll
    for (int i = 0; i < 4; ++i)
#pragma unroll
        for (int j = 0; j < 4; ++j) acc[i][j] = (f32x4){0.f, 0.f, 0.f, 0.f};

    for (int k0 = 0; k0 < K; k0 += BKK) {
        uint4 a0 = *(const uint4*)(A + (size_t)(m0 + r) * K + k0 + koff);
        uint4 a1 = *(const uint4*)(A + (size_t)(m0 + r) * K + k0 + koff + 8);
        uint4 b0 = *(const uint4*)(B + (size_t)(n0 + r) * K + k0 + koff);
        uint4 b1 = *(const uint4*)(B + (size_t)(n0 + r) * K + k0 + koff + 8);
        *(uint4*)(As + r * LDT + koff)     = a0;
        *(uint4*)(As + r * LDT + koff + 8) = a1;
        *(uint4*)(Bs + r * LDT + koff)     = b0;
        *(uint4*)(Bs + r * LDT + koff + 8) = b1;
        __syncthreads();
        f16x8 af[4], bfr[4];
#pragma unroll
        for (int i = 0; i < 4; ++i)
            af[i] = *(const f16x8*)(As + (wm + i * 16 + mrow) * LDT + kof);
#pragma unroll
        for (int j = 0; j < 4; ++j)
            bfr[j] = *(const f16x8*)(Bs + (wn + j * 16 + mrow) * LDT + kof);
#pragma unroll
        for (int i = 0; i < 4; ++i)
#pragma unroll
            for (int j = 0; j < 4; ++j)
                acc[i][j] = __builtin_amdgcn_mfma_f32_16x16x32_f16(af[i], bfr[j], acc[i][j], 0, 0, 0);
        __syncthreads();
    }
#pragma unroll
    for (int i = 0; i < 4; ++i) {
        const int rb = m0 + wm + i * 16 + crow;          // 4-aligned permuted row
        const float4 bbv = *(const float4*)(bsum + rb);  // bias for gates 0..3
        const int dd = rb >> 9;
        const int uu = (rb & 511) >> 2;                  // unit 0..127
#pragma unroll
        for (int j = 0; j < 4; ++j) {
            const int cm = n0 + wn + j * 16 + (lane & 15);
            const int b  = cm >> 11;          // batch
            const int s  = cm & 2047;         // step
            f16x4 v = {(f16)(acc[i][j][0] + bbv.x), (f16)(acc[i][j][1] + bbv.y),
                       (f16)(acc[i][j][2] + bbv.z), (f16)(acc[i][j][3] + bbv.w)};
            size_t fofs = ((((size_t)b * 256 + (s >> 3)) * 2 + dd) * 128 + uu) * 32
                          + (s & 7) * 4;
            *(f16x4*)(C + fofs) = v;
        }
    }
}

// ---------------- recurrent LSTM scan (MFMA, 1 chain/WG) ----------------
// WG = (batch b, dir d). 8 waves x 4 tiles. B = h broadcast to 16 cols.
// Lane (hi,ch): tile tt=ch>>2 (quad-uniform), gate g=ch&3 -> lane owns
// (unit u=(4wv+tt)*4+hi, gate g). Select = 15 cndmask; act = 2 trans; 4 DPP
// quad-broadcasts; cell = 2 trans. h: 16-slot LDS ring, hoisted base regs.
// MODE 1: stream tout; MODE 2: hfin.

template <int MODE>
__global__ void __attribute__((amdgpu_flat_work_group_size(512, 512),
                               amdgpu_waves_per_eu(2, 2))) k_lstm(
    const f16* __restrict__ G,              // [b][s/8][d][u][s%8][g] f16
    const f16* __restrict__ Whh,            // [1024][128] permuted+scaled
    f16* __restrict__ tout,                 // [131072][256] (MODE 1)
    float* __restrict__ hfin,               // [64][256] f32 (MODE 2)
    const int S) {
    const int wg = blockIdx.x;              // 128
    const int b  = wg >> 1, d = wg & 1;
    const int t  = threadIdx.x;
    const int l  = t & 63, wv = t >> 6;
    const int hi = l >> 4, ch = l & 15;
    const int tt = ch >> 2, g = ch & 3;

    __shared__ __align__(16) f16 ring[16][128];   // 16 slots x 256B

    // resident A-frags: w[q][ks] = tile (4wv+q), rows sub=ch, k = ks*32+hi*8
    f16x8 w[4][4];
#pragma unroll
    for (int q = 0; q < 4; ++q)
#pragma unroll
        for (int ks = 0; ks < 4; ++ks)
            w[q][ks] = *(const f16x8*)(Whh + ((size_t)d * 512 + (4 * wv + q) * 16 + ch) * 128
                                       + ks * 32 + hi * 8);

    for (int i = t; i < 1024; i += 512) ((uint32_t*)ring)[i] = 0;  // h(-1)=0

    const int u = (4 * wv + tt) * 4 + hi;   // the unit this lane's quad owns
    const f16* gp = G + ((((size_t)b * 256) * 2 + d) * 128 + u) * 32;

    // per-lane constants
    const bool t0 = (tt & 1) != 0, t1 = (tt & 2) != 0;
    const bool r0 = (g & 1) != 0, r1 = (g & 2) != 0;
    const bool pG = (g & 2) != 0;
    const int  shG = (g & 1) * 16;
    const float Aact = (g == 2) ? 1.f : 0.f;
    const float Bact = (g == 2) ? -2.f : 1.f;
    const bool wrt = (g == 0);

    uint4 gc[4], gn[4];                     // 64B G granule: 8 steps x f16x4
#pragma unroll
    for (int q = 0; q < 4; ++q) gc[q] = *(const uint4*)(gp + q * 8);

    const f32x4 Z = {0.f, 0.f, 0.f, 0.f};
    float c = 0.f;
    __syncthreads();

    for (int sb = 0; sb < S; sb += 8) {
        {   // prefetch next block's G granule (in flight across barriers)
            const size_t nb = (size_t)((sb + 8 < S) ? (sb >> 3) + 1 : (sb >> 3));
#pragma unroll
            for (int q = 0; q < 4; ++q) gn[q] = *(const uint4*)(gp + nb * 8192 + q * 8);
        }
        if (MODE == 1 && sb > 0 && t < 256) {   // stream block sb-8 -> tout
            const int jf = t >> 5, of = t & 31;
            uint2 hv = *(const uint2*)(&ring[((sb - 8) & 15) + jf][of * 4]);
            *(uint2*)(tout + ((size_t)b * 2048 + (sb - 8 + jf)) * 256 + d * 128 + of * 4) = hv;
        }
        // hoisted ring bases: all per-step ds offsets are immediates
        const int half = sb & 15;                       // 0 or 8
        const f16* rd0 = &ring[(half ^ 8) + 7][hi * 8]; // jj==0 reads slot half^8+7
        const f16* rdc = &ring[half][hi * 8];           // jj>=1: imm (jj-1)*256
        f16* wrp = &ring[half][u];                      // write: imm jj*256
#pragma unroll
        for (int jj = 0; jj < 8; ++jj) {
            const int s = sb + jj;
            const f16* hb = (jj == 0) ? rd0 : (rdc + (jj - 1) * 128);
            f16x8 b0 = *(const f16x8*)(hb);
            f16x8 b1 = *(const f16x8*)(hb + 32);
            f16x8 b2 = *(const f16x8*)(hb + 64);
            f16x8 b3 = *(const f16x8*)(hb + 96);
            f32x4 A0 = __builtin_amdgcn_mfma_f32_16x16x32_f16(w[0][0], b0, Z, 0, 0, 0);
            f32x4 A1 = __builtin_amdgcn_mfma_f32_16x16x32_f16(w[1][0], b0, Z, 0, 0, 0);
            f32x4 A2 = __builtin_amdgcn_mfma_f32_16x16x32_f16(w[2][0], b0, Z, 0, 0, 0);
            f32x4 A3 = __builtin_amdgcn_mfma_f32_16x16x32_f16(w[3][0], b0, Z, 0, 0, 0);
            A0 = __builtin_amdgcn_mfma_f32_16x16x32_f16(w[0][1], b1, A0, 0, 0, 0);
            A1 = __builtin_amdgcn_mfma_f32_16x16x32_f16(w[1][1], b1, A1, 0, 0, 0);
            A2 = __builtin_amdgcn_mfma_f32_16x16x32_f16(w[2][1], b1, A2, 0, 0, 0);
            A3 = __builtin_amdgcn_mfma_f32_16x16x32_f16(w[3][1], b1, A3, 0, 0, 0);
            A0 = __builtin_amdgcn_mfma_f32_16x16x32_f16(w[0][2], b2, A0, 0, 0, 0);
            A1 = __builtin_amdgcn_mfma_f32_16x16x32_f16(w[1][2], b2, A1, 0, 0, 0);
            A2 = __builtin_amdgcn_mfma_f32_16x16x32_f16(w[2][2], b2, A2, 0, 0, 0);
            A3 = __builtin_amdgcn_mfma_f32_16x16x32_f16(w[3][2], b2, A3, 0, 0, 0);
            A0 = __builtin_amdgcn_mfma_f32_16x16x32_f16(w[0][3], b3, A0, 0, 0, 0);
            A1 = __builtin_amdgcn_mfma_f32_16x16x32_f16(w[1][3], b3, A1, 0, 0, 0);
            A2 = __builtin_amdgcn_mfma_f32_16x16x32_f16(w[2][3], b3, A2, 0, 0, 0);
            A3 = __builtin_amdgcn_mfma_f32_16x16x32_f16(w[3][3], b3, A3, 0, 0, 0);
            // select acc tile (ch>>2) then C-reg (ch&3): v = preact(u, g)
            f32x4 X, Y, T;
#pragma unroll
            for (int e = 0; e < 4; ++e) {
                X[e] = t0 ? A1[e] : A0[e];
                Y[e] = t0 ? A3[e] : A2[e];
                T[e] = t1 ? Y[e] : X[e];
            }
            float xx = r0 ? T[1] : T[0];
            float yy = r0 ? T[3] : T[2];
            float v  = r1 ? yy : xx;
            // inject this lane's gate pre-act from the G granule
            uint32_t dw0 = (jj & 1) ? gc[jj >> 1].z : gc[jj >> 1].x;
            uint32_t dw1 = (jj & 1) ? gc[jj >> 1].w : gc[jj >> 1].y;
            uint32_t dsel = pG ? dw1 : dw0;
            v += (float)__builtin_bit_cast(f16, (uint16_t)(dsel >> shG));
            // unified activation: 2 trans (sign pre-folded into scaling)
            float wv_ = FRCP(1.f + FEXP2(v));
            float act = __builtin_fmaf(Bact, wv_, Aact);
            // quad-broadcast the 4 gates of this unit
            float gi = qperm<0x00>(act);
            float gf = qperm<0x55>(act);
            float gg = qperm<0xAA>(act);
            float go = qperm<0xFF>(act);
            c = __builtin_fmaf(gf, c, gi * gg);
            float tc = __builtin_fmaf(-2.f, FRCP(1.f + FEXP2(c * K_TANH)), 1.f);
            float hv = go * tc;
            if (wrt) *(wrp + jj * 128) = (f16)hv;
            if (MODE == 2 && s == S - 1 && wrt)
                hfin[(size_t)b * 256 + d * 128 + u] = hv;
            // LDS-only drain + barrier: G prefetch stays in flight
            __asm__ __volatile__("s_waitcnt lgkmcnt(0)\n\ts_barrier" ::: "memory");
        }
#pragma unroll
        for (int q = 0; q < 4; ++q) gc[q] = gn[q];
    }
    if (MODE == 1 && t < 256) {             // flush final block (steps S-8..S-1)
        const int jf = t >> 5, of = t & 31;
        uint2 hv = *(const uint2*)(&ring[((S - 8) & 15) + jf][of * 4]);
        *(uint2*)(tout + ((size_t)b * 2048 + (S - 8 + jf)) * 256 + d * 128 + of * 4) = hv;
    }
}

// ---------------- output projection ----------------

__global__ __launch_bounds__(128) void k_out(const float* __restrict__ hp,  // [64][256]
                                             const float* __restrict__ Wo,  // [88][256]
                                             const float* __restrict__ bo,  // [88]
                                             float* __restrict__ out) {     // [64][88]
    const int b = blockIdx.x;
    const int t = threadIdx.x;
    __shared__ float hs[256];
    hs[t] = hp[b * 256 + t];
    hs[t + 128] = hp[b * 256 + 128 + t];
    __syncthreads();
    if (t < 88) {
        float acc = bo[t];
        const float* wr = Wo + t * 256;
#pragma unroll 4
        for (int k = 0; k < 256; ++k) acc += wr[k] * hs[k];
        out[b * 88 + t] = acc;
    }
}

// ---------------- launch ----------------

extern "C" void kernel_launch(void* const* d_in, const int* in_sizes, int n_in,
                              void* d_out, int out_size, void* d_ws, size_t ws_size,
                              hipStream_t stream) {
    const float* x    = (const float*)d_in[0];
    const float* Wtih = (const float*)d_in[1];
    const float* Wthh = (const float*)d_in[2];
    const float* btih = (const float*)d_in[3];
    const float* bthh = (const float*)d_in[4];
    const float* Wpih = (const float*)d_in[5];
    const float* Wphh = (const float*)d_in[6];
    const float* bpih = (const float*)d_in[7];
    const float* bphh = (const float*)d_in[8];
    const float* Wo   = (const float*)d_in[9];
    const float* bo   = (const float*)d_in[10];

    char* ws = (char*)d_ws;
    f16*   xh    = (f16*)(ws + 0);            //  67,108,864 B  [131072][256]
    f16*   G     = (f16*)(ws + 67108864);     // 268,435,456 B  scan-block layout
    f16*   tout  = (f16*)(ws + 335544320);    //  67,108,864 B  [131072][256]
    f16*   wtih  = (f16*)(ws + 402653184);    //     524,288 B  permuted+scaled
    f16*   wthh  = (f16*)(ws + 403177472);    //     262,144 B
    f16*   wpih  = (f16*)(ws + 403439616);    //     524,288 B
    f16*   wphh  = (f16*)(ws + 403963904);    //     262,144 B
    float* bsT   = (float*)(ws + 404226048);  //       4,096 B
    float* bsP   = (float*)(ws + 404230144);  //       4,096 B
    float* hp    = (float*)(ws + 404226048);  //      65,536 B  (written by scan2)

    k_convert_x<<<16384, 256, 0, stream>>>(x, xh);
    k_convert_wp<<<128, 256, 0, stream>>>(Wtih, wtih, 5, 32768);
    k_convert_wp<<<64,  256, 0, stream>>>(Wthh, wthh, 4, 16384);
    k_convert_wp<<<128, 256, 0, stream>>>(Wpih, wpih, 5, 32768);
    k_convert_wp<<<64,  256, 0, stream>>>(Wphh, wphh, 4, 16384);
    k_bias<<<4, 256, 0, stream>>>(btih, bthh, bsT);
    k_bias<<<4, 256, 0, stream>>>(bpih, bphh, bsP);

    // G = (xh @ Wt_ih'^T) + bias, scan-block layout
    k_gemm<<<dim3(8, 1024), 256, 0, stream>>>(wtih, xh, G, bsT, 1024, 131072, 256);
    // time-level scan -> tout
    k_lstm<1><<<128, 512, 0, stream>>>(G, wthh, tout, nullptr, 2048);
    // G = (tout @ Wp_ih'^T) + bias
    k_gemm<<<dim3(8, 1024), 256, 0, stream>>>(wpih, tout, G, bsP, 1024, 131072, 256);
    // pitch-level scan -> final h
    k_lstm<2><<<128, 512, 0, stream>>>(G, wphh, nullptr, hp, 2048);
    // output projection
    k_out<<<64, 128, 0, stream>>>(hp, Wo, bo, (float*)d_out);
}